// Round 12
// baseline (4023.138 us; speedup 1.0000x reference)
//
#include <hip/hip_runtime.h>
#include <stdint.h>

typedef uint16_t u16;
typedef uint32_t u32;
typedef uint64_t u64;
typedef short short8 __attribute__((ext_vector_type(8)));
typedef float f32x4 __attribute__((ext_vector_type(4)));

#define DEV static __device__ __forceinline__

DEV u16 f2bf(float f){
  u32 x = __builtin_bit_cast(u32, f);
  return (u16)((x + 0x7fffu + ((x >> 16) & 1u)) >> 16);
}

DEV float bf2f(u16 u){
  u32 v = (u32)u << 16;
  return __builtin_bit_cast(float, v);
}

DEV f32x4 mfma16(short8 a, short8 b, f32x4 c){
  return __builtin_amdgcn_mfma_f32_16x16x32_bf16(a, b, c, 0, 0, 0);
}

DEV void async16(const void* g, void* l){
  __builtin_amdgcn_global_load_lds(
      (const __attribute__((address_space(1))) u32*)g,
      (__attribute__((address_space(3))) u32*)l, 16, 0, 0);
}

// ---------------------------------------------------------------- embedding (bf16 only; xb IS the residual stream)
__global__ __launch_bounds__(256)
void embed_kernel(const int* __restrict__ tid, const int* __restrict__ sid,
                  const float* __restrict__ tok, const float* __restrict__ pos,
                  const float* __restrict__ seg, u16* __restrict__ xb)
{
  const int row = blockIdx.x;          // b*512 + s
  const int s = row & 511;
  const int tk = tid[row], sg = sid[row];
  const int t = threadIdx.x;
#pragma unroll
  for (int e = 0; e < 3; ++e){
    int i = t + e*256;
    float v = tok[(u64)tk*768 + i] + seg[(u64)sg*768 + i] + pos[(u64)s*768 + i];
    xb[(u64)row*768 + i] = f2bf(v);
  }
}

// ---------------------------------------------------------------- fp32 -> bf16 (dense_w)
__global__ __launch_bounds__(256)
void cvt_bf16(const float4* __restrict__ in, ushort4* __restrict__ out, int n4)
{
  int i = blockIdx.x*256 + threadIdx.x;
  if (i >= n4) return;
  float4 f = in[i];
  ushort4 o;
  o.x = f2bf(f.x); o.y = f2bf(f.y); o.z = f2bf(f.z); o.w = f2bf(f.w);
  out[i] = o;
}

// ---------------------------------------------------------------- fused per-layer weight conversion
__global__ __launch_bounds__(256)
void cvt_layer(const float4* __restrict__ Wq, const float4* __restrict__ Wk,
               const float4* __restrict__ Wv, const float4* __restrict__ Wo,
               const float4* __restrict__ W1, const float4* __restrict__ W2,
               ushort4* __restrict__ wqkv, ushort4* __restrict__ wob,
               ushort4* __restrict__ w1b, ushort4* __restrict__ w2b)
{
  const int i = blockIdx.x*256 + threadIdx.x;   // < 1769472
  const int S = 147456;                         // 768*768/4
  float4 f; ushort4* dst; int di;
  if      (i <   S)       { f = Wq[i];            dst = wqkv; di = i; }
  else if (i < 2*S)       { f = Wk[i - S];        dst = wqkv; di = i; }
  else if (i < 3*S)       { f = Wv[i - 2*S];      dst = wqkv; di = i; }
  else if (i < 4*S)       { f = Wo[i - 3*S];      dst = wob;  di = i - 3*S; }
  else if (i < 4*S+589824){ f = W1[i - 4*S];      dst = w1b;  di = i - 4*S; }
  else                    { f = W2[i - 4*S-589824]; dst = w2b; di = i - 4*S - 589824; }
  ushort4 o;
  o.x = f2bf(f.x); o.y = f2bf(f.y); o.z = f2bf(f.z); o.w = f2bf(f.w);
  dst[di] = o;
}

// ---------------------------------------------------------------- bias concat (Q,K,V)
__global__ __launch_bounds__(256)
void concat_bias(const float* __restrict__ bq, const float* __restrict__ bk,
                 const float* __restrict__ bv, float* __restrict__ out)
{
  const int l = blockIdx.x;
  const int t = threadIdx.x;
#pragma unroll
  for (int e = 0; e < 3; ++e){
    int i = t + e*256;
    out[(u64)l*2304 + i]        = bq[(u64)l*768 + i];
    out[(u64)l*2304 + 768 + i]  = bk[(u64)l*768 + i];
    out[(u64)l*2304 + 1536 + i] = bv[(u64)l*768 + i];
  }
}

// ================================================================ 128x128 ring-3 GEMM
// EPI 0: fp32 store, optional fused residual add from bf16 xres (post-LN stream).
// EPI 1: bf16 store; V-column blocks (col>=1536, vt!=null) write transposed vT directly.
// EPI 2: bf16 store + exact GELU.
DEV void stage128(const u16* __restrict__ X, int ld, int limit,
                  int rowbase, int k0, u16* lds, int t)
{
  const int rl  = t >> 2;                             // 0..63
  const int col = (((t & 3) ^ ((t >> 3) & 3))) << 3;  // pre-swizzled source col
  int r0 = rowbase + rl;       if (r0 > limit-1) r0 = limit-1;
  int r1 = rowbase + rl + 64;  if (r1 > limit-1) r1 = limit-1;
  async16(X + (u64)r0*ld + k0 + col, lds + t*8);
  async16(X + (u64)r1*ld + k0 + col, lds + 2048 + t*8);
}

DEV short8 ldfrag(const u16* buf, int row, int slot){
  return *(const short8*)(buf + row*32 + (slot << 3));
}

template<int EPI>
__global__ __launch_bounds__(256)
void gemm3r(const u16* __restrict__ A, const u16* __restrict__ W,
            const float* __restrict__ bias, const u16* __restrict__ xres,
            u16* __restrict__ vt, void* __restrict__ Cout,
            int M, int N, int K, int GM)
{
  __shared__ u16 sm[24576];     // 48 KB
  const int t = threadIdx.x;
  const int w = t >> 6, l = t & 63;
  const int lr = l & 15, lg = l >> 4;
  const int wm = (w >> 1)*64, wn = (w & 1)*64;
  const int xr = (lr >> 1) & 3;
  const int slot = lg ^ xr;

  // bijective chunked XCD swizzle (m204), bm-fast
  const int nwg = gridDim.x, orig = blockIdx.x;
  const int q = nwg >> 3, r = nwg & 7;
  const int xcd = orig & 7, sl8 = orig >> 3;
  const int wgid = (xcd < r ? xcd*(q+1) : r*(q+1) + (xcd-r)*q) + sl8;
  const int bm = wgid % GM, bn = wgid / GM;

  f32x4 acc[4][4] = {};
  short8 af[4], bf[4];

  const int NT = K >> 5;
  // prologue: stage tiles 0,1
  stage128(A, K, M, bm*128,  0, sm,          t);
  stage128(W, K, N, bn*128,  0, sm + 4096,   t);
  stage128(A, K, M, bm*128, 32, sm + 8192,   t);
  stage128(W, K, N, bn*128, 32, sm + 12288,  t);
  asm volatile("s_waitcnt vmcnt(4)" ::: "memory");
  __builtin_amdgcn_s_barrier();

  for (int tt = 0; tt < NT; ++tt){
    const int rs  = (tt % 3) * 8192;
    const int rs2 = ((tt + 2) % 3) * 8192;
    const int k2  = (tt + 2) * 32;
    const bool st2 = (tt + 2) < NT;
    const u16* Ar = sm + rs;
    const u16* Br = sm + rs + 4096;

    // ---- phase A: read A mi0-1 + all B ; stage A(t+2) ; MFMA (mi0-1 x ni0-3) ----
    af[0] = ldfrag(Ar, wm + lr, slot);
    af[1] = ldfrag(Ar, wm + 16 + lr, slot);
#pragma unroll
    for (int ni = 0; ni < 4; ++ni) bf[ni] = ldfrag(Br, wn + ni*16 + lr, slot);
    if (st2) stage128(A, K, M, bm*128, k2, sm + rs2, t);
    __builtin_amdgcn_s_barrier();
    __builtin_amdgcn_s_setprio(1);
#pragma unroll
    for (int mi = 0; mi < 2; ++mi)
#pragma unroll
      for (int ni = 0; ni < 4; ++ni)
        acc[mi][ni] = mfma16(af[mi], bf[ni], acc[mi][ni]);
    __builtin_amdgcn_s_setprio(0);
    __builtin_amdgcn_s_barrier();

    // ---- phase B: read A mi2-3 ; stage B(t+2) ; MFMA (mi2-3 x ni0-3) ----
    af[2] = ldfrag(Ar, wm + 32 + lr, slot);
    af[3] = ldfrag(Ar, wm + 48 + lr, slot);
    if (st2) stage128(W, K, N, bn*128, k2, sm + rs2 + 4096, t);
    __builtin_amdgcn_s_barrier();
    __builtin_amdgcn_s_setprio(1);
#pragma unroll
    for (int mi = 2; mi < 4; ++mi)
#pragma unroll
      for (int ni = 0; ni < 4; ++ni)
        acc[mi][ni] = mfma16(af[mi], bf[ni], acc[mi][ni]);
    __builtin_amdgcn_s_setprio(0);
    if (st2) asm volatile("s_waitcnt vmcnt(4)" ::: "memory");   // tile t+1 resident
    else     asm volatile("s_waitcnt vmcnt(0)" ::: "memory");   // final drain
    __builtin_amdgcn_s_barrier();
  }

  // ---- epilogue ----
  __syncthreads();                      // staging LDS now reusable

  if constexpr (EPI == 1){
    if (vt && bn*128 + wn >= 1536){
      // V-column wave tile (64 rows x 64 cols, head-aligned): write vT transposed.
      u16* vbuf = sm + w*4736;          // [64][74] u16, stride 74 -> <=2-way banks
#pragma unroll
      for (int mi = 0; mi < 4; ++mi)
#pragma unroll
        for (int ni = 0; ni < 4; ++ni){
          int col = bn*128 + wn + ni*16 + lr;
          float bv = bias ? bias[col] : 0.f;
#pragma unroll
          for (int rr = 0; rr < 4; ++rr)
            vbuf[(mi*16 + lg*4 + rr)*74 + ni*16 + lr] = f2bf(acc[mi][ni][rr] + bv);
        }
      asm volatile("s_waitcnt lgkmcnt(0)" ::: "memory");
      const int row0w = bm*128 + wm;
      const int b_ = row0w >> 9, s0 = row0w & 511;
      const int h_ = (bn*128 + wn - 1536) >> 6;
#pragma unroll
      for (int e = 0; e < 8; ++e){
        int d = e*8 + (l >> 3), s8 = (l & 7)*8;
        short8 ov;
#pragma unroll
        for (int i = 0; i < 8; ++i) ov[i] = (short)vbuf[(s8 + i)*74 + d];
        *(short8*)(vt + ((u64)(b_*12 + h_)*64 + d)*512 + s0 + s8) = ov;
      }
      return;
    }
  }

  constexpr int EPLD = 68;
  float* epw = (float*)sm + w*(16*EPLD);
#pragma unroll
  for (int mi = 0; mi < 4; ++mi){
#pragma unroll
    for (int ni = 0; ni < 4; ++ni){
      int col = bn*128 + wn + ni*16 + lr;
      float bv = bias ? bias[col < N ? col : N-1] : 0.f;
#pragma unroll
      for (int rr = 0; rr < 4; ++rr){
        float v = acc[mi][ni][rr] + bv;
        if constexpr (EPI == 2) v = 0.5f*v*(1.0f + erff(v*0.70710678118f));
        epw[(lg*4 + rr)*EPLD + ni*16 + lr] = v;
      }
    }
    asm volatile("s_waitcnt lgkmcnt(0)" ::: "memory");
    if constexpr (EPI == 0){
#pragma unroll
      for (int ps = 0; ps < 4; ++ps){
        int rloc = ps*4 + (l >> 4);
        int row = bm*128 + wm + mi*16 + rloc;
        int col = bn*128 + wn + (l & 15)*4;
        f32x4 v4 = *(const f32x4*)&epw[rloc*EPLD + (l & 15)*4];
        if (row < M){
          if (col + 3 < N){
            if (xres){                     // fused post-LN residual (bf16 stream)
              ushort4 x4 = *(const ushort4*)(xres + (u64)row*N + col);
              v4[0] += bf2f(x4.x); v4[1] += bf2f(x4.y);
              v4[2] += bf2f(x4.z); v4[3] += bf2f(x4.w);
            }
            *(f32x4*)((float*)Cout + (u64)row*N + col) = v4;
          } else {
#pragma unroll
            for (int j = 0; j < 4; ++j)
              if (col + j < N){
                float vv = v4[j];
                if (xres) vv += bf2f(xres[(u64)row*N + col + j]);
                ((float*)Cout)[(u64)row*N + col + j] = vv;
              }
          }
        }
      }
    } else {
#pragma unroll
      for (int ps = 0; ps < 2; ++ps){
        int rloc = ps*8 + (l >> 3);
        int row = bm*128 + wm + mi*16 + rloc;
        int col = bn*128 + wn + (l & 7)*8;
        f32x4 a4 = *(const f32x4*)&epw[rloc*EPLD + (l & 7)*8];
        f32x4 b4 = *(const f32x4*)&epw[rloc*EPLD + (l & 7)*8 + 4];
        short8 o8;
        o8[0] = f2bf(a4[0]); o8[1] = f2bf(a4[1]); o8[2] = f2bf(a4[2]); o8[3] = f2bf(a4[3]);
        o8[4] = f2bf(b4[0]); o8[5] = f2bf(b4[1]); o8[6] = f2bf(b4[2]); o8[7] = f2bf(b4[3]);
        if (row < M){
          if (col + 7 < N) *(short8*)((u16*)Cout + (u64)row*N + col) = o8;
          else {
#pragma unroll
            for (int j = 0; j < 8; ++j)
              if (col + j < N) ((u16*)Cout)[(u64)row*N + col + j] = (u16)o8[j];
          }
        }
      }
    }
    asm volatile("s_waitcnt lgkmcnt(0)" ::: "memory");
  }
}

// ---------------------------------------------------------------- 256x256 8-wave GEMM (vocab)
DEV void stage_tile(const u16* __restrict__ X, int ld, int limit,
                    int rowbase, int k0, u16* lds, int t)
{
  const int rl  = t >> 2;
  const int col = (((t & 3) ^ ((t >> 3) & 3))) << 3;
  int r0 = rowbase + rl;        if (r0 > limit-1) r0 = limit-1;
  int r1 = rowbase + rl + 128;  if (r1 > limit-1) r1 = limit-1;
  async16(X + (u64)r0*ld + k0 + col, lds + t*8);
  async16(X + (u64)r1*ld + k0 + col, lds + 4096 + t*8);
}

__global__ __launch_bounds__(512)
void gemm8v(const u16* __restrict__ A, const u16* __restrict__ W,
            const float* __restrict__ bias, float* __restrict__ Cout,
            int M, int N, int K, int GM)
{
  __shared__ u16 sm[49152];
  u16* Ab = sm;
  u16* Bb = sm + 24576;
  const int t = threadIdx.x;
  const int w = t >> 6, l = t & 63;
  const int lr = l & 15, lg = l >> 4;
  const int wr = w >> 2, wc = w & 3;
  const int xr = (lr >> 1) & 3;
  const int slot = lg ^ xr;

  const int nwg = gridDim.x, orig = blockIdx.x;
  const int q = nwg >> 3, r = nwg & 7;
  const int xcd = orig & 7, sl8 = orig >> 3;
  const int wgid = (xcd < r ? xcd*(q+1) : r*(q+1) + (xcd-r)*q) + sl8;
  const int bm = wgid % GM, bn = wgid / GM;

  f32x4 acc[8][4] = {};
  short8 afr[4], bfr[4];

  const int NT = K >> 5;
  stage_tile(A, K, M, bm*256,  0, Ab,        t);
  stage_tile(W, K, N, bn*256,  0, Bb,        t);
  stage_tile(A, K, M, bm*256, 32, Ab + 8192, t);
  stage_tile(W, K, N, bn*256, 32, Bb + 8192, t);
  asm volatile("s_waitcnt vmcnt(4)" ::: "memory");
  __builtin_amdgcn_s_barrier();

  for (int tt = 0; tt < NT; ++tt){
    const int rs = (tt % 3) * 8192;
    const int rs2 = ((tt + 2) % 3) * 8192;
    const int k2 = (tt + 2)*32;
    const u16* Ar = Ab + rs;
    const u16* Br = Bb + rs;
#pragma unroll
    for (int mi = 0; mi < 4; ++mi) afr[mi] = ldfrag(Ar, wr*128 + mi*16 + lr, slot);
#pragma unroll
    for (int ni = 0; ni < 4; ++ni) bfr[ni] = ldfrag(Br, wc*64 + ni*16 + lr, slot);
    if (tt + 2 < NT) stage_tile(A, K, M, bm*256, k2, Ab + rs2, t);
    __builtin_amdgcn_s_barrier();
    __builtin_amdgcn_s_setprio(1);
#pragma unroll
    for (int mi = 0; mi < 4; ++mi)
#pragma unroll
      for (int ni = 0; ni < 4; ++ni)
        acc[mi][ni] = mfma16(afr[mi], bfr[ni], acc[mi][ni]);
    __builtin_amdgcn_s_setprio(0);
    __builtin_amdgcn_s_barrier();
#pragma unroll
    for (int mi = 0; mi < 4; ++mi) afr[mi] = ldfrag(Ar, wr*128 + (mi+4)*16 + lr, slot);
    if (tt + 2 < NT) stage_tile(W, K, N, bn*256, k2, Bb + rs2, t);
    __builtin_amdgcn_s_barrier();
    __builtin_amdgcn_s_setprio(1);
#pragma unroll
    for (int mi = 0; mi < 4; ++mi)
#pragma unroll
      for (int ni = 0; ni < 4; ++ni)
        acc[mi+4][ni] = mfma16(afr[mi], bfr[ni], acc[mi+4][ni]);
    __builtin_amdgcn_s_setprio(0);
    if (tt + 2 < NT) asm volatile("s_waitcnt vmcnt(4)" ::: "memory");
    else             asm volatile("s_waitcnt vmcnt(0)" ::: "memory");
    __builtin_amdgcn_s_barrier();
  }

  __syncthreads();
  constexpr int EPLD = 68;
  float* epw = (float*)sm + w*(16*EPLD);
  const int growbase = bm*256 + wr*128;
  const int gcolbase = bn*256 + wc*64;
#pragma unroll
  for (int mi = 0; mi < 8; ++mi){
#pragma unroll
    for (int ni = 0; ni < 4; ++ni){
      int col = gcolbase + ni*16 + lr;
      float bv = bias ? bias[col < N ? col : N-1] : 0.f;
#pragma unroll
      for (int rr = 0; rr < 4; ++rr)
        epw[(lg*4 + rr)*EPLD + ni*16 + lr] = acc[mi][ni][rr] + bv;
    }
    asm volatile("s_waitcnt lgkmcnt(0)" ::: "memory");
#pragma unroll
    for (int ps = 0; ps < 4; ++ps){
      int rloc = ps*4 + (l >> 4);
      int row = growbase + mi*16 + rloc;
      int col = gcolbase + (l & 15)*4;
      f32x4 v4 = *(const f32x4*)&epw[rloc*EPLD + (l & 15)*4];
      if (row < M){
        if (col + 3 < N) *(f32x4*)(Cout + (u64)row*N + col) = v4;
        else {
#pragma unroll
          for (int j = 0; j < 4; ++j)
            if (col + j < N) Cout[(u64)row*N + col + j] = v4[j];
        }
      }
    }
    asm volatile("s_waitcnt lgkmcnt(0)" ::: "memory");
  }
}

// ---------------------------------------------------------------- flash attention, no-max softmax, 64 q-rows/wave
// K fragments loaded once per jt, shared across 4 Q-fragments (4x MFMA per load);
// s computed/exp'd per-fragment to bound live registers.
__global__ __launch_bounds__(256)
void attn_kernel(const u16* __restrict__ qkv, const u16* __restrict__ vt,
                 u16* __restrict__ ob)
{
  __shared__ u16 p_lds[4][64][72];
  const int t = threadIdx.x, w = t >> 6, ll = t & 63;
  const int lr = ll & 15, lg = ll >> 4;
  const int qt = blockIdx.x, h = blockIdx.y, b = blockIdx.z;
  const int q0 = qt*256 + w*64;
  const float C = 0.125f * 1.44269504f;   // 1/sqrt(64) * log2(e)

  short8 qf[4][2];
#pragma unroll
  for (int f = 0; f < 4; ++f){
    const u16* qrow = qkv + (u64)(b*512 + q0 + f*16 + lr)*2304 + h*64 + 8*lg;
    qf[f][0] = *(const short8*)qrow;
    qf[f][1] = *(const short8*)(qrow + 32);
  }

  const u16* kbh = qkv + (u64)(b*512)*2304 + 768 + h*64;
  const u16* vth = vt + (u64)(b*12 + h)*64*512;

  f32x4 lacc[4] = {};
  f32x4 o_acc[4][4] = {};

  for (int jt = 0; jt < 8; ++jt){
    const int jb = jt*64;
    // K fragments once per tile
    short8 kf[4][2];
#pragma unroll
    for (int jn = 0; jn < 4; ++jn){
      const u16* kr = kbh + (u64)(jb + jn*16 + lr)*2304 + 8*lg;
      kf[jn][0] = *(const short8*)kr;
      kf[jn][1] = *(const short8*)(kr + 32);
    }
    // per-fragment: QK^T -> exp -> p_lds (keeps s live only per fragment)
#pragma unroll
    for (int f = 0; f < 4; ++f){
      f32x4 s[4] = {};
#pragma unroll
      for (int jn = 0; jn < 4; ++jn){
        s[jn] = mfma16(qf[f][0], kf[jn][0], s[jn]);
        s[jn] = mfma16(qf[f][1], kf[jn][1], s[jn]);
      }
#pragma unroll
      for (int jn = 0; jn < 4; ++jn)
#pragma unroll
        for (int r = 0; r < 4; ++r){
          float pv = exp2f(s[jn][r]*C);
          lacc[f][r] += pv;
          p_lds[w][f*16 + 4*lg + r][jn*16 + lr] = f2bf(pv);
        }
    }
    // per-wave LDS region: wave-local wait suffices (DS pipe in-order per wave)
    asm volatile("s_waitcnt lgkmcnt(0)" ::: "memory");
    short8 pa[4][2];
#pragma unroll
    for (int f = 0; f < 4; ++f){
      pa[f][0] = *(const short8*)(&p_lds[w][f*16 + lr][8*lg]);
      pa[f][1] = *(const short8*)(&p_lds[w][f*16 + lr][32 + 8*lg]);
    }
#pragma unroll
    for (int nd = 0; nd < 4; ++nd){
      const u16* vr = vth + (u64)(nd*16 + lr)*512 + jb + 8*lg;
      short8 vf0 = *(const short8*)vr;
      short8 vf1 = *(const short8*)(vr + 32);
#pragma unroll
      for (int f = 0; f < 4; ++f){
        o_acc[f][nd] = mfma16(pa[f][0], vf0, o_acc[f][nd]);
        o_acc[f][nd] = mfma16(pa[f][1], vf1, o_acc[f][nd]);
      }
    }
    asm volatile("s_waitcnt lgkmcnt(0)" ::: "memory");
  }
  float l_r[4][4];
#pragma unroll
  for (int f = 0; f < 4; ++f)
#pragma unroll
    for (int r = 0; r < 4; ++r){
      float v = lacc[f][r];
#pragma unroll
      for (int m = 1; m < 16; m <<= 1) v += __shfl_xor(v, m);
      l_r[f][r] = 1.f / v;
    }
#pragma unroll
  for (int f = 0; f < 4; ++f)
#pragma unroll
    for (int nd = 0; nd < 4; ++nd)
#pragma unroll
      for (int r = 0; r < 4; ++r)
        p_lds[w][f*16 + 4*lg + r][nd*16 + lr] = f2bf(o_acc[f][nd][r]*l_r[f][r]);
  asm volatile("s_waitcnt lgkmcnt(0)" ::: "memory");
#pragma unroll
  for (int ps = 0; ps < 8; ++ps){
    int row = ps*8 + (ll >> 3);
    short8 ov = *(const short8*)(&p_lds[w][row][(ll & 7)*8]);
    *(short8*)(ob + (u64)(b*512 + q0 + row)*768 + h*64 + (ll & 7)*8) = ov;
  }
}

// ---------------------------------------------------------------- LayerNorm: reads fp32 y (GEMM+bias+residual), writes bf16 xb
__global__ __launch_bounds__(256)
void ln_only(const float* __restrict__ yin,
             const float* __restrict__ g, const float* __restrict__ be,
             u16* __restrict__ xbout)
{
  __shared__ float sred[8];
  const int row = blockIdx.x, t = threadIdx.x;
  const int w = t >> 6, ll = t & 63;
  float v[3]; float s = 0.f, sq = 0.f;
#pragma unroll
  for (int e = 0; e < 3; ++e){
    int i = t + e*256;
    float val = yin[(u64)row*768 + i];
    v[e] = val; s += val; sq += val*val;
  }
#pragma unroll
  for (int m = 1; m < 64; m <<= 1){ s += __shfl_xor(s, m); sq += __shfl_xor(sq, m); }
  if (ll == 0){ sred[w] = s; sred[4 + w] = sq; }
  __syncthreads();
  s  = sred[0] + sred[1] + sred[2] + sred[3];
  sq = sred[4] + sred[5] + sred[6] + sred[7];
  const float mean = s*(1.f/768.f);
  const float rstd = rsqrtf(sq*(1.f/768.f) - mean*mean + 1e-5f);
#pragma unroll
  for (int e = 0; e < 3; ++e){
    int i = t + e*256;
    xbout[(u64)row*768 + i] = f2bf((v[e] - mean)*rstd*g[i] + be[i]);
  }
}

// ---------------------------------------------------------------- gather masked rows
__global__ __launch_bounds__(256)
void gather_rows(const u16* __restrict__ xb, const int* __restrict__ mids,
                 u16* __restrict__ xg)
{
  const int row = blockIdx.x;
  const int b = row / 77;
  const int src = b*512 + mids[row];
  const int t = threadIdx.x;
#pragma unroll
  for (int e = 0; e < 3; ++e){
    int i = t + e*256;
    xg[(u64)row*768 + i] = xb[(u64)src*768 + i];
  }
}

// ---------------------------------------------------------------- host
extern "C" void kernel_launch(void* const* d_in, const int* in_sizes, int n_in,
                              void* d_out, int out_size, void* d_ws, size_t ws_size,
                              hipStream_t stream)
{
  const int*   token_ids  = (const int*)  d_in[0];
  const int*   segment_ids= (const int*)  d_in[1];
  const int*   mask_ids   = (const int*)  d_in[2];
  const float* tok_emb    = (const float*)d_in[3];
  const float* pos_emb    = (const float*)d_in[4];
  const float* seg_emb    = (const float*)d_in[5];
  const float* dense_w    = (const float*)d_in[6];
  const float* dense_b    = (const float*)d_in[7];
  const float* Wq = (const float*)d_in[8];  const float* bq = (const float*)d_in[9];
  const float* Wk = (const float*)d_in[10]; const float* bk = (const float*)d_in[11];
  const float* Wv = (const float*)d_in[12]; const float* bv = (const float*)d_in[13];
  const float* Wo = (const float*)d_in[14]; const float* bo = (const float*)d_in[15];
  const float* W1 = (const float*)d_in[16]; const float* b1 = (const float*)d_in[17];
  const float* W2 = (const float*)d_in[18]; const float* b2 = (const float*)d_in[19];
  const float* g1 = (const float*)d_in[20]; const float* be1= (const float*)d_in[21];
  const float* g2 = (const float*)d_in[22]; const float* be2= (const float*)d_in[23];

  char* p = (char*)d_ws;
  auto alloc = [&](size_t bytes)->char*{
    char* r = p; p += (bytes + 255) & ~(size_t)255; return r;
  };
  const u64 T = 8192;
  float* y    = (float*)alloc(T*768*4);   // fp32 GEMM+residual scratch
  u16*   xb   = (u16*)  alloc(T*768*2);   // bf16 post-LN residual stream
  u16*   qkvb = (u16*)  alloc(T*2304*2);  // Q,K parts (V goes straight to vT)
  u16*   vT   = (u16*)  alloc(T*768*2);
  u16*   obuf = (u16*)  alloc(T*768*2);
  u16*   h1b  = (u16*)  alloc(T*3072*2);
  u16*   xg   = (u16*)  alloc((u64)1232*768*2);
  u16*   wqkv = (u16*)  alloc((u64)2304*768*2);
  u16*   wob  = (u16*)  alloc((u64)768*768*2);
  u16*   w1b  = (u16*)  alloc((u64)3072*768*2);
  u16*   w2b  = (u16*)  alloc((u64)3072*768*2);
  float* bqkv = (float*)alloc((u64)12*2304*4);
  u16*   dwb  = h1b;   // reuse (dense_w bf16 = 46.9 MB <= h1b 50.3 MB)

  if ((size_t)(p - (char*)d_ws) > ws_size) return;

  embed_kernel<<<dim3(8192), dim3(256), 0, stream>>>(
      token_ids, segment_ids, tok_emb, pos_emb, seg_emb, xb);
  concat_bias<<<dim3(12), dim3(256), 0, stream>>>(bq, bk, bv, bqkv);

  for (int l = 0; l < 12; ++l){
    cvt_layer<<<dim3(6912), dim3(256), 0, stream>>>(
        (const float4*)(Wq + (u64)l*589824), (const float4*)(Wk + (u64)l*589824),
        (const float4*)(Wv + (u64)l*589824), (const float4*)(Wo + (u64)l*589824),
        (const float4*)(W1 + (u64)l*2359296), (const float4*)(W2 + (u64)l*2359296),
        (ushort4*)wqkv, (ushort4*)wob, (ushort4*)w1b, (ushort4*)w2b);

    // QKV: [8192,768] @ [2304,768]^T -> Q,K to qkvb; V transposed to vT in-epilogue
    gemm3r<1><<<dim3(64*18), dim3(256), 0, stream>>>(xb, wqkv, bqkv + (u64)l*2304, nullptr,
                                                     vT, qkvb, 8192, 2304, 768, 64);

    attn_kernel<<<dim3(2, 12, 16), dim3(256), 0, stream>>>(qkvb, vT, obuf);

    // o-proj + residual: y = obuf@Wo^T + bo + bf2f(xb)
    gemm3r<0><<<dim3(64*6), dim3(256), 0, stream>>>(obuf, wob, bo + (u64)l*768, xb,
                                                    nullptr, y, 8192, 768, 768, 64);
    ln_only<<<dim3(8192), dim3(256), 0, stream>>>(y, g1 + (u64)l*768, be1 + (u64)l*768, xb);

    // FFN1: [8192,768] @ [3072,768]^T -> bf16 + GELU
    gemm3r<2><<<dim3(64*24), dim3(256), 0, stream>>>(xb, w1b, b1 + (u64)l*3072, nullptr,
                                                     nullptr, h1b, 8192, 3072, 768, 64);
    // FFN2 + residual: y = h1b@W2^T + b2 + bf2f(xb)
    gemm3r<0><<<dim3(64*6), dim3(256), 0, stream>>>(h1b, w2b, b2 + (u64)l*768, xb,
                                                    nullptr, y, 8192, 768, 3072, 64);
    ln_only<<<dim3(8192), dim3(256), 0, stream>>>(y, g2 + (u64)l*768, be2 + (u64)l*768, xb);
  }

  gather_rows<<<dim3(1232), dim3(256), 0, stream>>>(xb, mask_ids, xg);
  cvt_bf16<<<dim3(22892), dim3(256), 0, stream>>>((const float4*)dense_w, (ushort4*)dwb, 5860224);
  gemm8v<<<dim3(5*120), dim3(512), 0, stream>>>(xg, dwb, dense_b, (float*)d_out,
                                                1232, 30522, 768, 5);
}

// Round 13
// 3673.230 us; speedup vs baseline: 1.0953x; 1.0953x over previous
//
#include <hip/hip_runtime.h>
#include <stdint.h>

typedef uint16_t u16;
typedef uint32_t u32;
typedef uint64_t u64;
typedef short short8 __attribute__((ext_vector_type(8)));
typedef float f32x4 __attribute__((ext_vector_type(4)));

#define DEV static __device__ __forceinline__

DEV u16 f2bf(float f){
  u32 x = __builtin_bit_cast(u32, f);
  return (u16)((x + 0x7fffu + ((x >> 16) & 1u)) >> 16);
}

DEV float bf2f(u16 u){
  u32 v = (u32)u << 16;
  return __builtin_bit_cast(float, v);
}

DEV f32x4 mfma16(short8 a, short8 b, f32x4 c){
  return __builtin_amdgcn_mfma_f32_16x16x32_bf16(a, b, c, 0, 0, 0);
}

DEV void async16(const void* g, void* l){
  __builtin_amdgcn_global_load_lds(
      (const __attribute__((address_space(1))) u32*)g,
      (__attribute__((address_space(3))) u32*)l, 16, 0, 0);
}

// ---------------------------------------------------------------- embedding (bf16 only; xb IS the residual stream)
__global__ __launch_bounds__(256)
void embed_kernel(const int* __restrict__ tid, const int* __restrict__ sid,
                  const float* __restrict__ tok, const float* __restrict__ pos,
                  const float* __restrict__ seg, u16* __restrict__ xb)
{
  const int row = blockIdx.x;          // b*512 + s
  const int s = row & 511;
  const int tk = tid[row], sg = sid[row];
  const int t = threadIdx.x;
#pragma unroll
  for (int e = 0; e < 3; ++e){
    int i = t + e*256;
    float v = tok[(u64)tk*768 + i] + seg[(u64)sg*768 + i] + pos[(u64)s*768 + i];
    xb[(u64)row*768 + i] = f2bf(v);
  }
}

// ---------------------------------------------------------------- fp32 -> bf16 (dense_w)
__global__ __launch_bounds__(256)
void cvt_bf16(const float4* __restrict__ in, ushort4* __restrict__ out, int n4)
{
  int i = blockIdx.x*256 + threadIdx.x;
  if (i >= n4) return;
  float4 f = in[i];
  ushort4 o;
  o.x = f2bf(f.x); o.y = f2bf(f.y); o.z = f2bf(f.z); o.w = f2bf(f.w);
  out[i] = o;
}

// ---------------------------------------------------------------- fused per-layer weight conversion
__global__ __launch_bounds__(256)
void cvt_layer(const float4* __restrict__ Wq, const float4* __restrict__ Wk,
               const float4* __restrict__ Wv, const float4* __restrict__ Wo,
               const float4* __restrict__ W1, const float4* __restrict__ W2,
               ushort4* __restrict__ wqkv, ushort4* __restrict__ wob,
               ushort4* __restrict__ w1b, ushort4* __restrict__ w2b)
{
  const int i = blockIdx.x*256 + threadIdx.x;   // < 1769472
  const int S = 147456;                         // 768*768/4
  float4 f; ushort4* dst; int di;
  if      (i <   S)       { f = Wq[i];            dst = wqkv; di = i; }
  else if (i < 2*S)       { f = Wk[i - S];        dst = wqkv; di = i; }
  else if (i < 3*S)       { f = Wv[i - 2*S];      dst = wqkv; di = i; }
  else if (i < 4*S)       { f = Wo[i - 3*S];      dst = wob;  di = i - 3*S; }
  else if (i < 4*S+589824){ f = W1[i - 4*S];      dst = w1b;  di = i - 4*S; }
  else                    { f = W2[i - 4*S-589824]; dst = w2b; di = i - 4*S - 589824; }
  ushort4 o;
  o.x = f2bf(f.x); o.y = f2bf(f.y); o.z = f2bf(f.z); o.w = f2bf(f.w);
  dst[di] = o;
}

// ---------------------------------------------------------------- bias concat (Q,K,V)
__global__ __launch_bounds__(256)
void concat_bias(const float* __restrict__ bq, const float* __restrict__ bk,
                 const float* __restrict__ bv, float* __restrict__ out)
{
  const int l = blockIdx.x;
  const int t = threadIdx.x;
#pragma unroll
  for (int e = 0; e < 3; ++e){
    int i = t + e*256;
    out[(u64)l*2304 + i]        = bq[(u64)l*768 + i];
    out[(u64)l*2304 + 768 + i]  = bk[(u64)l*768 + i];
    out[(u64)l*2304 + 1536 + i] = bv[(u64)l*768 + i];
  }
}

// ================================================================ 128x128 ring-3 GEMM
// EPI 0: fp32 store, optional fused residual add from bf16 xres (post-LN stream).
// EPI 1: bf16 store; V-column blocks (col>=1536, vt!=null) write transposed vT directly.
// EPI 2: bf16 store + exact GELU.
DEV void stage128(const u16* __restrict__ X, int ld, int limit,
                  int rowbase, int k0, u16* lds, int t)
{
  const int rl  = t >> 2;                             // 0..63
  const int col = (((t & 3) ^ ((t >> 3) & 3))) << 3;  // pre-swizzled source col
  int r0 = rowbase + rl;       if (r0 > limit-1) r0 = limit-1;
  int r1 = rowbase + rl + 64;  if (r1 > limit-1) r1 = limit-1;
  async16(X + (u64)r0*ld + k0 + col, lds + t*8);
  async16(X + (u64)r1*ld + k0 + col, lds + 2048 + t*8);
}

DEV short8 ldfrag(const u16* buf, int row, int slot){
  return *(const short8*)(buf + row*32 + (slot << 3));
}

template<int EPI>
__global__ __launch_bounds__(256)
void gemm3r(const u16* __restrict__ A, const u16* __restrict__ W,
            const float* __restrict__ bias, const u16* __restrict__ xres,
            u16* __restrict__ vt, void* __restrict__ Cout,
            int M, int N, int K, int GM)
{
  __shared__ u16 sm[24576];     // 48 KB
  const int t = threadIdx.x;
  const int w = t >> 6, l = t & 63;
  const int lr = l & 15, lg = l >> 4;
  const int wm = (w >> 1)*64, wn = (w & 1)*64;
  const int xr = (lr >> 1) & 3;
  const int slot = lg ^ xr;

  // bijective chunked XCD swizzle (m204), bm-fast
  const int nwg = gridDim.x, orig = blockIdx.x;
  const int q = nwg >> 3, r = nwg & 7;
  const int xcd = orig & 7, sl8 = orig >> 3;
  const int wgid = (xcd < r ? xcd*(q+1) : r*(q+1) + (xcd-r)*q) + sl8;
  const int bm = wgid % GM, bn = wgid / GM;

  f32x4 acc[4][4] = {};
  short8 af[4], bf[4];

  const int NT = K >> 5;
  // prologue: stage tiles 0,1
  stage128(A, K, M, bm*128,  0, sm,          t);
  stage128(W, K, N, bn*128,  0, sm + 4096,   t);
  stage128(A, K, M, bm*128, 32, sm + 8192,   t);
  stage128(W, K, N, bn*128, 32, sm + 12288,  t);
  asm volatile("s_waitcnt vmcnt(4)" ::: "memory");
  __builtin_amdgcn_s_barrier();

  for (int tt = 0; tt < NT; ++tt){
    const int rs  = (tt % 3) * 8192;
    const int rs2 = ((tt + 2) % 3) * 8192;
    const int k2  = (tt + 2) * 32;
    const bool st2 = (tt + 2) < NT;
    const u16* Ar = sm + rs;
    const u16* Br = sm + rs + 4096;

    // ---- phase A: read A mi0-1 + all B ; stage A(t+2) ; MFMA (mi0-1 x ni0-3) ----
    af[0] = ldfrag(Ar, wm + lr, slot);
    af[1] = ldfrag(Ar, wm + 16 + lr, slot);
#pragma unroll
    for (int ni = 0; ni < 4; ++ni) bf[ni] = ldfrag(Br, wn + ni*16 + lr, slot);
    if (st2) stage128(A, K, M, bm*128, k2, sm + rs2, t);
    __builtin_amdgcn_s_barrier();
    __builtin_amdgcn_s_setprio(1);
#pragma unroll
    for (int mi = 0; mi < 2; ++mi)
#pragma unroll
      for (int ni = 0; ni < 4; ++ni)
        acc[mi][ni] = mfma16(af[mi], bf[ni], acc[mi][ni]);
    __builtin_amdgcn_s_setprio(0);
    __builtin_amdgcn_s_barrier();

    // ---- phase B: read A mi2-3 ; stage B(t+2) ; MFMA (mi2-3 x ni0-3) ----
    af[2] = ldfrag(Ar, wm + 32 + lr, slot);
    af[3] = ldfrag(Ar, wm + 48 + lr, slot);
    if (st2) stage128(W, K, N, bn*128, k2, sm + rs2 + 4096, t);
    __builtin_amdgcn_s_barrier();
    __builtin_amdgcn_s_setprio(1);
#pragma unroll
    for (int mi = 2; mi < 4; ++mi)
#pragma unroll
      for (int ni = 0; ni < 4; ++ni)
        acc[mi][ni] = mfma16(af[mi], bf[ni], acc[mi][ni]);
    __builtin_amdgcn_s_setprio(0);
    if (st2) asm volatile("s_waitcnt vmcnt(4)" ::: "memory");   // tile t+1 resident
    else     asm volatile("s_waitcnt vmcnt(0)" ::: "memory");   // final drain
    __builtin_amdgcn_s_barrier();
  }

  // ---- epilogue ----
  __syncthreads();                      // staging LDS now reusable

  if constexpr (EPI == 1){
    if (vt && bn*128 + wn >= 1536){
      // V-column wave tile (64 rows x 64 cols, head-aligned): write vT transposed.
      u16* vbuf = sm + w*4736;          // [64][74] u16, stride 74 -> <=2-way banks
#pragma unroll
      for (int mi = 0; mi < 4; ++mi)
#pragma unroll
        for (int ni = 0; ni < 4; ++ni){
          int col = bn*128 + wn + ni*16 + lr;
          float bv = bias ? bias[col] : 0.f;
#pragma unroll
          for (int rr = 0; rr < 4; ++rr)
            vbuf[(mi*16 + lg*4 + rr)*74 + ni*16 + lr] = f2bf(acc[mi][ni][rr] + bv);
        }
      asm volatile("s_waitcnt lgkmcnt(0)" ::: "memory");
      const int row0w = bm*128 + wm;
      const int b_ = row0w >> 9, s0 = row0w & 511;
      const int h_ = (bn*128 + wn - 1536) >> 6;
#pragma unroll
      for (int e = 0; e < 8; ++e){
        int d = e*8 + (l >> 3), s8 = (l & 7)*8;
        short8 ov;
#pragma unroll
        for (int i = 0; i < 8; ++i) ov[i] = (short)vbuf[(s8 + i)*74 + d];
        *(short8*)(vt + ((u64)(b_*12 + h_)*64 + d)*512 + s0 + s8) = ov;
      }
      return;
    }
  }

  constexpr int EPLD = 68;
  float* epw = (float*)sm + w*(16*EPLD);
#pragma unroll
  for (int mi = 0; mi < 4; ++mi){
#pragma unroll
    for (int ni = 0; ni < 4; ++ni){
      int col = bn*128 + wn + ni*16 + lr;
      float bv = bias ? bias[col < N ? col : N-1] : 0.f;
#pragma unroll
      for (int rr = 0; rr < 4; ++rr){
        float v = acc[mi][ni][rr] + bv;
        if constexpr (EPI == 2) v = 0.5f*v*(1.0f + erff(v*0.70710678118f));
        epw[(lg*4 + rr)*EPLD + ni*16 + lr] = v;
      }
    }
    asm volatile("s_waitcnt lgkmcnt(0)" ::: "memory");
    if constexpr (EPI == 0){
#pragma unroll
      for (int ps = 0; ps < 4; ++ps){
        int rloc = ps*4 + (l >> 4);
        int row = bm*128 + wm + mi*16 + rloc;
        int col = bn*128 + wn + (l & 15)*4;
        f32x4 v4 = *(const f32x4*)&epw[rloc*EPLD + (l & 15)*4];
        if (row < M){
          if (col + 3 < N){
            if (xres){                     // fused post-LN residual (bf16 stream)
              ushort4 x4 = *(const ushort4*)(xres + (u64)row*N + col);
              v4[0] += bf2f(x4.x); v4[1] += bf2f(x4.y);
              v4[2] += bf2f(x4.z); v4[3] += bf2f(x4.w);
            }
            *(f32x4*)((float*)Cout + (u64)row*N + col) = v4;
          } else {
#pragma unroll
            for (int j = 0; j < 4; ++j)
              if (col + j < N){
                float vv = v4[j];
                if (xres) vv += bf2f(xres[(u64)row*N + col + j]);
                ((float*)Cout)[(u64)row*N + col + j] = vv;
              }
          }
        }
      }
    } else {
#pragma unroll
      for (int ps = 0; ps < 2; ++ps){
        int rloc = ps*8 + (l >> 3);
        int row = bm*128 + wm + mi*16 + rloc;
        int col = bn*128 + wn + (l & 7)*8;
        f32x4 a4 = *(const f32x4*)&epw[rloc*EPLD + (l & 7)*8];
        f32x4 b4 = *(const f32x4*)&epw[rloc*EPLD + (l & 7)*8 + 4];
        short8 o8;
        o8[0] = f2bf(a4[0]); o8[1] = f2bf(a4[1]); o8[2] = f2bf(a4[2]); o8[3] = f2bf(a4[3]);
        o8[4] = f2bf(b4[0]); o8[5] = f2bf(b4[1]); o8[6] = f2bf(b4[2]); o8[7] = f2bf(b4[3]);
        if (row < M){
          if (col + 7 < N) *(short8*)((u16*)Cout + (u64)row*N + col) = o8;
          else {
#pragma unroll
            for (int j = 0; j < 8; ++j)
              if (col + j < N) ((u16*)Cout)[(u64)row*N + col + j] = (u16)o8[j];
          }
        }
      }
    }
    asm volatile("s_waitcnt lgkmcnt(0)" ::: "memory");
  }
}

// ---------------------------------------------------------------- 256x256 8-wave GEMM (vocab)
DEV void stage_tile(const u16* __restrict__ X, int ld, int limit,
                    int rowbase, int k0, u16* lds, int t)
{
  const int rl  = t >> 2;
  const int col = (((t & 3) ^ ((t >> 3) & 3))) << 3;
  int r0 = rowbase + rl;        if (r0 > limit-1) r0 = limit-1;
  int r1 = rowbase + rl + 128;  if (r1 > limit-1) r1 = limit-1;
  async16(X + (u64)r0*ld + k0 + col, lds + t*8);
  async16(X + (u64)r1*ld + k0 + col, lds + 4096 + t*8);
}

__global__ __launch_bounds__(512)
void gemm8v(const u16* __restrict__ A, const u16* __restrict__ W,
            const float* __restrict__ bias, float* __restrict__ Cout,
            int M, int N, int K, int GM)
{
  __shared__ u16 sm[49152];
  u16* Ab = sm;
  u16* Bb = sm + 24576;
  const int t = threadIdx.x;
  const int w = t >> 6, l = t & 63;
  const int lr = l & 15, lg = l >> 4;
  const int wr = w >> 2, wc = w & 3;
  const int xr = (lr >> 1) & 3;
  const int slot = lg ^ xr;

  const int nwg = gridDim.x, orig = blockIdx.x;
  const int q = nwg >> 3, r = nwg & 7;
  const int xcd = orig & 7, sl8 = orig >> 3;
  const int wgid = (xcd < r ? xcd*(q+1) : r*(q+1) + (xcd-r)*q) + sl8;
  const int bm = wgid % GM, bn = wgid / GM;

  f32x4 acc[8][4] = {};
  short8 afr[4], bfr[4];

  const int NT = K >> 5;
  stage_tile(A, K, M, bm*256,  0, Ab,        t);
  stage_tile(W, K, N, bn*256,  0, Bb,        t);
  stage_tile(A, K, M, bm*256, 32, Ab + 8192, t);
  stage_tile(W, K, N, bn*256, 32, Bb + 8192, t);
  asm volatile("s_waitcnt vmcnt(4)" ::: "memory");
  __builtin_amdgcn_s_barrier();

  for (int tt = 0; tt < NT; ++tt){
    const int rs = (tt % 3) * 8192;
    const int rs2 = ((tt + 2) % 3) * 8192;
    const int k2 = (tt + 2)*32;
    const u16* Ar = Ab + rs;
    const u16* Br = Bb + rs;
#pragma unroll
    for (int mi = 0; mi < 4; ++mi) afr[mi] = ldfrag(Ar, wr*128 + mi*16 + lr, slot);
#pragma unroll
    for (int ni = 0; ni < 4; ++ni) bfr[ni] = ldfrag(Br, wc*64 + ni*16 + lr, slot);
    if (tt + 2 < NT) stage_tile(A, K, M, bm*256, k2, Ab + rs2, t);
    __builtin_amdgcn_s_barrier();
    __builtin_amdgcn_s_setprio(1);
#pragma unroll
    for (int mi = 0; mi < 4; ++mi)
#pragma unroll
      for (int ni = 0; ni < 4; ++ni)
        acc[mi][ni] = mfma16(afr[mi], bfr[ni], acc[mi][ni]);
    __builtin_amdgcn_s_setprio(0);
    __builtin_amdgcn_s_barrier();
#pragma unroll
    for (int mi = 0; mi < 4; ++mi) afr[mi] = ldfrag(Ar, wr*128 + (mi+4)*16 + lr, slot);
    if (tt + 2 < NT) stage_tile(W, K, N, bn*256, k2, Bb + rs2, t);
    __builtin_amdgcn_s_barrier();
    __builtin_amdgcn_s_setprio(1);
#pragma unroll
    for (int mi = 0; mi < 4; ++mi)
#pragma unroll
      for (int ni = 0; ni < 4; ++ni)
        acc[mi+4][ni] = mfma16(afr[mi], bfr[ni], acc[mi+4][ni]);
    __builtin_amdgcn_s_setprio(0);
    if (tt + 2 < NT) asm volatile("s_waitcnt vmcnt(4)" ::: "memory");
    else             asm volatile("s_waitcnt vmcnt(0)" ::: "memory");
    __builtin_amdgcn_s_barrier();
  }

  __syncthreads();
  constexpr int EPLD = 68;
  float* epw = (float*)sm + w*(16*EPLD);
  const int growbase = bm*256 + wr*128;
  const int gcolbase = bn*256 + wc*64;
#pragma unroll
  for (int mi = 0; mi < 8; ++mi){
#pragma unroll
    for (int ni = 0; ni < 4; ++ni){
      int col = gcolbase + ni*16 + lr;
      float bv = bias ? bias[col < N ? col : N-1] : 0.f;
#pragma unroll
      for (int rr = 0; rr < 4; ++rr)
        epw[(lg*4 + rr)*EPLD + ni*16 + lr] = acc[mi][ni][rr] + bv;
    }
    asm volatile("s_waitcnt lgkmcnt(0)" ::: "memory");
#pragma unroll
    for (int ps = 0; ps < 4; ++ps){
      int rloc = ps*4 + (l >> 4);
      int row = growbase + mi*16 + rloc;
      int col = gcolbase + (l & 15)*4;
      f32x4 v4 = *(const f32x4*)&epw[rloc*EPLD + (l & 15)*4];
      if (row < M){
        if (col + 3 < N) *(f32x4*)(Cout + (u64)row*N + col) = v4;
        else {
#pragma unroll
          for (int j = 0; j < 4; ++j)
            if (col + j < N) Cout[(u64)row*N + col + j] = v4[j];
        }
      }
    }
    asm volatile("s_waitcnt lgkmcnt(0)" ::: "memory");
  }
}

// ---------------------------------------------------------------- flash attention, no-max softmax, 32 q-rows/wave
__global__ __launch_bounds__(256)
void attn_kernel(const u16* __restrict__ qkv, const u16* __restrict__ vt,
                 u16* __restrict__ ob)
{
  __shared__ u16 p_lds[4][32][72];
  const int t = threadIdx.x, w = t >> 6, ll = t & 63;
  const int lr = ll & 15, lg = ll >> 4;
  const int qt = blockIdx.x, h = blockIdx.y, b = blockIdx.z;
  const int q0 = qt*128 + w*32;
  const float C = 0.125f * 1.44269504f;   // 1/sqrt(64) * log2(e)

  short8 qf[2][2];
#pragma unroll
  for (int f = 0; f < 2; ++f){
    const u16* qrow = qkv + (u64)(b*512 + q0 + f*16 + lr)*2304 + h*64 + 8*lg;
    qf[f][0] = *(const short8*)qrow;
    qf[f][1] = *(const short8*)(qrow + 32);
  }

  const u16* kbh = qkv + (u64)(b*512)*2304 + 768 + h*64;
  const u16* vth = vt + (u64)(b*12 + h)*64*512;

  f32x4 lacc[2] = {};
  f32x4 o_acc[2][4] = {};

  for (int jt = 0; jt < 8; ++jt){
    const int jb = jt*64;
    f32x4 s[2][4] = {};
#pragma unroll
    for (int jn = 0; jn < 4; ++jn){
      const u16* kr = kbh + (u64)(jb + jn*16 + lr)*2304 + 8*lg;
      short8 kf0 = *(const short8*)kr;
      short8 kf1 = *(const short8*)(kr + 32);
#pragma unroll
      for (int f = 0; f < 2; ++f){
        s[f][jn] = mfma16(qf[f][0], kf0, s[f][jn]);
        s[f][jn] = mfma16(qf[f][1], kf1, s[f][jn]);
      }
    }
#pragma unroll
    for (int f = 0; f < 2; ++f)
#pragma unroll
      for (int jn = 0; jn < 4; ++jn)
#pragma unroll
        for (int r = 0; r < 4; ++r){
          float pv = exp2f(s[f][jn][r]*C);
          lacc[f][r] += pv;
          p_lds[w][f*16 + 4*lg + r][jn*16 + lr] = f2bf(pv);
        }
    // per-wave LDS region: wave-local wait suffices (DS pipe in-order per wave)
    asm volatile("s_waitcnt lgkmcnt(0)" ::: "memory");
    short8 pa[2][2];
#pragma unroll
    for (int f = 0; f < 2; ++f){
      pa[f][0] = *(const short8*)(&p_lds[w][f*16 + lr][8*lg]);
      pa[f][1] = *(const short8*)(&p_lds[w][f*16 + lr][32 + 8*lg]);
    }
#pragma unroll
    for (int nd = 0; nd < 4; ++nd){
      const u16* vr = vth + (u64)(nd*16 + lr)*512 + jb + 8*lg;
      short8 vf0 = *(const short8*)vr;
      short8 vf1 = *(const short8*)(vr + 32);
#pragma unroll
      for (int f = 0; f < 2; ++f){
        o_acc[f][nd] = mfma16(pa[f][0], vf0, o_acc[f][nd]);
        o_acc[f][nd] = mfma16(pa[f][1], vf1, o_acc[f][nd]);
      }
    }
    asm volatile("s_waitcnt lgkmcnt(0)" ::: "memory");
  }
  float l_r[2][4];
#pragma unroll
  for (int f = 0; f < 2; ++f)
#pragma unroll
    for (int r = 0; r < 4; ++r){
      float v = lacc[f][r];
#pragma unroll
      for (int m = 1; m < 16; m <<= 1) v += __shfl_xor(v, m);
      l_r[f][r] = 1.f / v;
    }
#pragma unroll
  for (int f = 0; f < 2; ++f)
#pragma unroll
    for (int nd = 0; nd < 4; ++nd)
#pragma unroll
      for (int r = 0; r < 4; ++r)
        p_lds[w][f*16 + 4*lg + r][nd*16 + lr] = f2bf(o_acc[f][nd][r]*l_r[f][r]);
  asm volatile("s_waitcnt lgkmcnt(0)" ::: "memory");
#pragma unroll
  for (int ps = 0; ps < 4; ++ps){
    int row = ps*8 + (ll >> 3);
    short8 ov = *(const short8*)(&p_lds[w][row][(ll & 7)*8]);
    *(short8*)(ob + (u64)(b*512 + q0 + row)*768 + h*64 + (ll & 7)*8) = ov;
  }
}

// ---------------------------------------------------------------- LayerNorm: reads fp32 y (GEMM+bias+residual), writes bf16 xb
__global__ __launch_bounds__(256)
void ln_only(const float* __restrict__ yin,
             const float* __restrict__ g, const float* __restrict__ be,
             u16* __restrict__ xbout)
{
  __shared__ float sred[8];
  const int row = blockIdx.x, t = threadIdx.x;
  const int w = t >> 6, ll = t & 63;
  float v[3]; float s = 0.f, sq = 0.f;
#pragma unroll
  for (int e = 0; e < 3; ++e){
    int i = t + e*256;
    float val = yin[(u64)row*768 + i];
    v[e] = val; s += val; sq += val*val;
  }
#pragma unroll
  for (int m = 1; m < 64; m <<= 1){ s += __shfl_xor(s, m); sq += __shfl_xor(sq, m); }
  if (ll == 0){ sred[w] = s; sred[4 + w] = sq; }
  __syncthreads();
  s  = sred[0] + sred[1] + sred[2] + sred[3];
  sq = sred[4] + sred[5] + sred[6] + sred[7];
  const float mean = s*(1.f/768.f);
  const float rstd = rsqrtf(sq*(1.f/768.f) - mean*mean + 1e-5f);
#pragma unroll
  for (int e = 0; e < 3; ++e){
    int i = t + e*256;
    xbout[(u64)row*768 + i] = f2bf((v[e] - mean)*rstd*g[i] + be[i]);
  }
}

// ---------------------------------------------------------------- gather masked rows
__global__ __launch_bounds__(256)
void gather_rows(const u16* __restrict__ xb, const int* __restrict__ mids,
                 u16* __restrict__ xg)
{
  const int row = blockIdx.x;
  const int b = row / 77;
  const int src = b*512 + mids[row];
  const int t = threadIdx.x;
#pragma unroll
  for (int e = 0; e < 3; ++e){
    int i = t + e*256;
    xg[(u64)row*768 + i] = xb[(u64)src*768 + i];
  }
}

// ---------------------------------------------------------------- host
extern "C" void kernel_launch(void* const* d_in, const int* in_sizes, int n_in,
                              void* d_out, int out_size, void* d_ws, size_t ws_size,
                              hipStream_t stream)
{
  const int*   token_ids  = (const int*)  d_in[0];
  const int*   segment_ids= (const int*)  d_in[1];
  const int*   mask_ids   = (const int*)  d_in[2];
  const float* tok_emb    = (const float*)d_in[3];
  const float* pos_emb    = (const float*)d_in[4];
  const float* seg_emb    = (const float*)d_in[5];
  const float* dense_w    = (const float*)d_in[6];
  const float* dense_b    = (const float*)d_in[7];
  const float* Wq = (const float*)d_in[8];  const float* bq = (const float*)d_in[9];
  const float* Wk = (const float*)d_in[10]; const float* bk = (const float*)d_in[11];
  const float* Wv = (const float*)d_in[12]; const float* bv = (const float*)d_in[13];
  const float* Wo = (const float*)d_in[14]; const float* bo = (const float*)d_in[15];
  const float* W1 = (const float*)d_in[16]; const float* b1 = (const float*)d_in[17];
  const float* W2 = (const float*)d_in[18]; const float* b2 = (const float*)d_in[19];
  const float* g1 = (const float*)d_in[20]; const float* be1= (const float*)d_in[21];
  const float* g2 = (const float*)d_in[22]; const float* be2= (const float*)d_in[23];

  char* p = (char*)d_ws;
  auto alloc = [&](size_t bytes)->char*{
    char* r = p; p += (bytes + 255) & ~(size_t)255; return r;
  };
  const u64 T = 8192;
  float* y    = (float*)alloc(T*768*4);   // fp32 GEMM+residual scratch
  u16*   xb   = (u16*)  alloc(T*768*2);   // bf16 post-LN residual stream
  u16*   qkvb = (u16*)  alloc(T*2304*2);  // Q,K parts (V goes straight to vT)
  u16*   vT   = (u16*)  alloc(T*768*2);
  u16*   obuf = (u16*)  alloc(T*768*2);
  u16*   h1b  = (u16*)  alloc(T*3072*2);
  u16*   xg   = (u16*)  alloc((u64)1232*768*2);
  u16*   wqkv = (u16*)  alloc((u64)2304*768*2);
  u16*   wob  = (u16*)  alloc((u64)768*768*2);
  u16*   w1b  = (u16*)  alloc((u64)3072*768*2);
  u16*   w2b  = (u16*)  alloc((u64)3072*768*2);
  float* bqkv = (float*)alloc((u64)12*2304*4);
  u16*   dwb  = h1b;   // reuse (dense_w bf16 = 46.9 MB <= h1b 50.3 MB)

  if ((size_t)(p - (char*)d_ws) > ws_size) return;

  embed_kernel<<<dim3(8192), dim3(256), 0, stream>>>(
      token_ids, segment_ids, tok_emb, pos_emb, seg_emb, xb);
  concat_bias<<<dim3(12), dim3(256), 0, stream>>>(bq, bk, bv, bqkv);

  for (int l = 0; l < 12; ++l){
    cvt_layer<<<dim3(6912), dim3(256), 0, stream>>>(
        (const float4*)(Wq + (u64)l*589824), (const float4*)(Wk + (u64)l*589824),
        (const float4*)(Wv + (u64)l*589824), (const float4*)(Wo + (u64)l*589824),
        (const float4*)(W1 + (u64)l*2359296), (const float4*)(W2 + (u64)l*2359296),
        (ushort4*)wqkv, (ushort4*)wob, (ushort4*)w1b, (ushort4*)w2b);

    // QKV: [8192,768] @ [2304,768]^T -> Q,K to qkvb; V transposed to vT in-epilogue
    gemm3r<1><<<dim3(64*18), dim3(256), 0, stream>>>(xb, wqkv, bqkv + (u64)l*2304, nullptr,
                                                     vT, qkvb, 8192, 2304, 768, 64);

    attn_kernel<<<dim3(4, 12, 16), dim3(256), 0, stream>>>(qkvb, vT, obuf);

    // o-proj + residual: y = obuf@Wo^T + bo + bf2f(xb)
    gemm3r<0><<<dim3(64*6), dim3(256), 0, stream>>>(obuf, wob, bo + (u64)l*768, xb,
                                                    nullptr, y, 8192, 768, 768, 64);
    ln_only<<<dim3(8192), dim3(256), 0, stream>>>(y, g1 + (u64)l*768, be1 + (u64)l*768, xb);

    // FFN1: [8192,768] @ [3072,768]^T -> bf16 + GELU
    gemm3r<2><<<dim3(64*24), dim3(256), 0, stream>>>(xb, w1b, b1 + (u64)l*3072, nullptr,
                                                     nullptr, h1b, 8192, 3072, 768, 64);
    // FFN2 + residual: y = h1b@W2^T + b2 + bf2f(xb)
    gemm3r<0><<<dim3(64*6), dim3(256), 0, stream>>>(h1b, w2b, b2 + (u64)l*768, xb,
                                                    nullptr, y, 8192, 768, 3072, 64);
    ln_only<<<dim3(8192), dim3(256), 0, stream>>>(y, g2 + (u64)l*768, be2 + (u64)l*768, xb);
  }

  gather_rows<<<dim3(1232), dim3(256), 0, stream>>>(xb, mask_ids, xg);
  cvt_bf16<<<dim3(22892), dim3(256), 0, stream>>>((const float4*)dense_w, (ushort4*)dwb, 5860224);
  gemm8v<<<dim3(5*120), dim3(512), 0, stream>>>(xg, dwb, dense_b, (float*)d_out,
                                                1232, 30522, 768, 5);
}

// Round 14
// 3608.600 us; speedup vs baseline: 1.1149x; 1.0179x over previous
//
#include <hip/hip_runtime.h>
#include <stdint.h>

typedef uint16_t u16;
typedef uint32_t u32;
typedef uint64_t u64;
typedef short short8 __attribute__((ext_vector_type(8)));
typedef float f32x4 __attribute__((ext_vector_type(4)));

#define DEV static __device__ __forceinline__

DEV u16 f2bf(float f){
  u32 x = __builtin_bit_cast(u32, f);
  return (u16)((x + 0x7fffu + ((x >> 16) & 1u)) >> 16);
}

DEV float bf2f(u16 u){
  u32 v = (u32)u << 16;
  return __builtin_bit_cast(float, v);
}

DEV f32x4 mfma16(short8 a, short8 b, f32x4 c){
  return __builtin_amdgcn_mfma_f32_16x16x32_bf16(a, b, c, 0, 0, 0);
}

DEV void async16(const void* g, void* l){
  __builtin_amdgcn_global_load_lds(
      (const __attribute__((address_space(1))) u32*)g,
      (__attribute__((address_space(3))) u32*)l, 16, 0, 0);
}

// ---------------------------------------------------------------- embedding (bf16 only; xb IS the residual stream)
__global__ __launch_bounds__(256)
void embed_kernel(const int* __restrict__ tid, const int* __restrict__ sid,
                  const float* __restrict__ tok, const float* __restrict__ pos,
                  const float* __restrict__ seg, u16* __restrict__ xb)
{
  const int row = blockIdx.x;          // b*512 + s
  const int s = row & 511;
  const int tk = tid[row], sg = sid[row];
  const int t = threadIdx.x;
#pragma unroll
  for (int e = 0; e < 3; ++e){
    int i = t + e*256;
    float v = tok[(u64)tk*768 + i] + seg[(u64)sg*768 + i] + pos[(u64)s*768 + i];
    xb[(u64)row*768 + i] = f2bf(v);
  }
}

// ---------------------------------------------------------------- fp32 -> bf16 (dense_w)
__global__ __launch_bounds__(256)
void cvt_bf16(const float4* __restrict__ in, ushort4* __restrict__ out, int n4)
{
  int i = blockIdx.x*256 + threadIdx.x;
  if (i >= n4) return;
  float4 f = in[i];
  ushort4 o;
  o.x = f2bf(f.x); o.y = f2bf(f.y); o.z = f2bf(f.z); o.w = f2bf(f.w);
  out[i] = o;
}

// ---------------------------------------------------------------- per-layer weight conversion core
DEV void cvt_body(int i,
                  const float4* __restrict__ Wq, const float4* __restrict__ Wk,
                  const float4* __restrict__ Wv, const float4* __restrict__ Wo,
                  const float4* __restrict__ W1, const float4* __restrict__ W2,
                  ushort4* __restrict__ wqkv, ushort4* __restrict__ wob,
                  ushort4* __restrict__ w1b, ushort4* __restrict__ w2b)
{
  const int S = 147456;                         // 768*768/4
  float4 f; ushort4* dst; int di;
  if      (i <   S)       { f = Wq[i];            dst = wqkv; di = i; }
  else if (i < 2*S)       { f = Wk[i - S];        dst = wqkv; di = i; }
  else if (i < 3*S)       { f = Wv[i - 2*S];      dst = wqkv; di = i; }
  else if (i < 4*S)       { f = Wo[i - 3*S];      dst = wob;  di = i - 3*S; }
  else if (i < 4*S+589824){ f = W1[i - 4*S];      dst = w1b;  di = i - 4*S; }
  else                    { f = W2[i - 4*S-589824]; dst = w2b; di = i - 4*S - 589824; }
  ushort4 o;
  o.x = f2bf(f.x); o.y = f2bf(f.y); o.z = f2bf(f.z); o.w = f2bf(f.w);
  dst[di] = o;
}

__global__ __launch_bounds__(256)
void cvt_layer(const float4* __restrict__ Wq, const float4* __restrict__ Wk,
               const float4* __restrict__ Wv, const float4* __restrict__ Wo,
               const float4* __restrict__ W1, const float4* __restrict__ W2,
               ushort4* __restrict__ wqkv, ushort4* __restrict__ wob,
               ushort4* __restrict__ w1b, ushort4* __restrict__ w2b)
{
  cvt_body(blockIdx.x*256 + threadIdx.x, Wq, Wk, Wv, Wo, W1, W2, wqkv, wob, w1b, w2b);
}

// ---------------------------------------------------------------- bias concat (Q,K,V)
__global__ __launch_bounds__(256)
void concat_bias(const float* __restrict__ bq, const float* __restrict__ bk,
                 const float* __restrict__ bv, float* __restrict__ out)
{
  const int l = blockIdx.x;
  const int t = threadIdx.x;
#pragma unroll
  for (int e = 0; e < 3; ++e){
    int i = t + e*256;
    out[(u64)l*2304 + i]        = bq[(u64)l*768 + i];
    out[(u64)l*2304 + 768 + i]  = bk[(u64)l*768 + i];
    out[(u64)l*2304 + 1536 + i] = bv[(u64)l*768 + i];
  }
}

// ---------------------------------------------------------------- LayerNorm core: one wave per row, no barriers
DEV void ln_row(const float* __restrict__ yr, const float* __restrict__ g,
                const float* __restrict__ be, u16* __restrict__ xr, int ll)
{
  f32x4 v[3]; float s = 0.f, sq = 0.f;
#pragma unroll
  for (int e = 0; e < 3; ++e){
    v[e] = *(const f32x4*)(yr + e*256 + ll*4);
#pragma unroll
    for (int j = 0; j < 4; ++j){ s += v[e][j]; sq += v[e][j]*v[e][j]; }
  }
#pragma unroll
  for (int m = 1; m < 64; m <<= 1){ s += __shfl_xor(s, m); sq += __shfl_xor(sq, m); }
  const float mean = s*(1.f/768.f);
  const float rstd = rsqrtf(sq*(1.f/768.f) - mean*mean + 1e-5f);
#pragma unroll
  for (int e = 0; e < 3; ++e){
    f32x4 gv = *(const f32x4*)(g  + e*256 + ll*4);
    f32x4 bv = *(const f32x4*)(be + e*256 + ll*4);
    ushort4 o;
    o.x = f2bf((v[e][0] - mean)*rstd*gv[0] + bv[0]);
    o.y = f2bf((v[e][1] - mean)*rstd*gv[1] + bv[1]);
    o.z = f2bf((v[e][2] - mean)*rstd*gv[2] + bv[2]);
    o.w = f2bf((v[e][3] - mean)*rstd*gv[3] + bv[3]);
    *(ushort4*)(xr + e*256 + ll*4) = o;
  }
}

__global__ __launch_bounds__(256)
void ln_wave(const float* __restrict__ yin, const float* __restrict__ g,
             const float* __restrict__ be, u16* __restrict__ xbout)
{
  const int t = threadIdx.x, w = t >> 6, ll = t & 63;
  const u64 row = (u64)blockIdx.x*4 + w;
  ln_row(yin + row*768, g, be, xbout + row*768, ll);
}

// fused: blocks [0,2048) do LN; blocks [2048, 2048+6912) convert next layer's weights
__global__ __launch_bounds__(256)
void ln2cvt(const float* __restrict__ yin, const float* __restrict__ g,
            const float* __restrict__ be, u16* __restrict__ xbout,
            const float4* __restrict__ Wq, const float4* __restrict__ Wk,
            const float4* __restrict__ Wv, const float4* __restrict__ Wo,
            const float4* __restrict__ W1, const float4* __restrict__ W2,
            ushort4* __restrict__ wqkv, ushort4* __restrict__ wob,
            ushort4* __restrict__ w1b, ushort4* __restrict__ w2b)
{
  if (blockIdx.x < 2048){
    const int t = threadIdx.x, w = t >> 6, ll = t & 63;
    const u64 row = (u64)blockIdx.x*4 + w;
    ln_row(yin + row*768, g, be, xbout + row*768, ll);
  } else {
    cvt_body((blockIdx.x - 2048)*256 + threadIdx.x,
             Wq, Wk, Wv, Wo, W1, W2, wqkv, wob, w1b, w2b);
  }
}

// ================================================================ 128x128 ring-3 GEMM
// EPI 0: fp32 store, optional fused residual add from bf16 xres (post-LN stream).
// EPI 1: bf16 store; V-column blocks (col>=1536, vt!=null) write transposed vT directly.
// EPI 2: bf16 store + exact GELU.
DEV void stage128(const u16* __restrict__ X, int ld, int limit,
                  int rowbase, int k0, u16* lds, int t)
{
  const int rl  = t >> 2;                             // 0..63
  const int col = (((t & 3) ^ ((t >> 3) & 3))) << 3;  // pre-swizzled source col
  int r0 = rowbase + rl;       if (r0 > limit-1) r0 = limit-1;
  int r1 = rowbase + rl + 64;  if (r1 > limit-1) r1 = limit-1;
  async16(X + (u64)r0*ld + k0 + col, lds + t*8);
  async16(X + (u64)r1*ld + k0 + col, lds + 2048 + t*8);
}

DEV short8 ldfrag(const u16* buf, int row, int slot){
  return *(const short8*)(buf + row*32 + (slot << 3));
}

template<int EPI>
__global__ __launch_bounds__(256)
void gemm3r(const u16* __restrict__ A, const u16* __restrict__ W,
            const float* __restrict__ bias, const u16* __restrict__ xres,
            u16* __restrict__ vt, void* __restrict__ Cout,
            int M, int N, int K, int GM)
{
  __shared__ u16 sm[24576];     // 48 KB
  const int t = threadIdx.x;
  const int w = t >> 6, l = t & 63;
  const int lr = l & 15, lg = l >> 4;
  const int wm = (w >> 1)*64, wn = (w & 1)*64;
  const int xr = (lr >> 1) & 3;
  const int slot = lg ^ xr;

  // bijective chunked XCD swizzle (m204), bm-fast
  const int nwg = gridDim.x, orig = blockIdx.x;
  const int q = nwg >> 3, r = nwg & 7;
  const int xcd = orig & 7, sl8 = orig >> 3;
  const int wgid = (xcd < r ? xcd*(q+1) : r*(q+1) + (xcd-r)*q) + sl8;
  const int bm = wgid % GM, bn = wgid / GM;

  f32x4 acc[4][4] = {};
  short8 af[4], bf[4];

  const int NT = K >> 5;
  // prologue: stage tiles 0,1
  stage128(A, K, M, bm*128,  0, sm,          t);
  stage128(W, K, N, bn*128,  0, sm + 4096,   t);
  stage128(A, K, M, bm*128, 32, sm + 8192,   t);
  stage128(W, K, N, bn*128, 32, sm + 12288,  t);
  asm volatile("s_waitcnt vmcnt(4)" ::: "memory");
  __builtin_amdgcn_s_barrier();

  for (int tt = 0; tt < NT; ++tt){
    const int rs  = (tt % 3) * 8192;
    const int rs2 = ((tt + 2) % 3) * 8192;
    const int k2  = (tt + 2) * 32;
    const bool st2 = (tt + 2) < NT;
    const u16* Ar = sm + rs;
    const u16* Br = sm + rs + 4096;

    // ---- phase A: read A mi0-1 + all B ; stage A(t+2) ; MFMA (mi0-1 x ni0-3) ----
    af[0] = ldfrag(Ar, wm + lr, slot);
    af[1] = ldfrag(Ar, wm + 16 + lr, slot);
#pragma unroll
    for (int ni = 0; ni < 4; ++ni) bf[ni] = ldfrag(Br, wn + ni*16 + lr, slot);
    if (st2) stage128(A, K, M, bm*128, k2, sm + rs2, t);
    __builtin_amdgcn_s_barrier();
    __builtin_amdgcn_s_setprio(1);
#pragma unroll
    for (int mi = 0; mi < 2; ++mi)
#pragma unroll
      for (int ni = 0; ni < 4; ++ni)
        acc[mi][ni] = mfma16(af[mi], bf[ni], acc[mi][ni]);
    __builtin_amdgcn_s_setprio(0);
    __builtin_amdgcn_s_barrier();

    // ---- phase B: read A mi2-3 ; stage B(t+2) ; MFMA (mi2-3 x ni0-3) ----
    af[2] = ldfrag(Ar, wm + 32 + lr, slot);
    af[3] = ldfrag(Ar, wm + 48 + lr, slot);
    if (st2) stage128(W, K, N, bn*128, k2, sm + rs2 + 4096, t);
    __builtin_amdgcn_s_barrier();
    __builtin_amdgcn_s_setprio(1);
#pragma unroll
    for (int mi = 2; mi < 4; ++mi)
#pragma unroll
      for (int ni = 0; ni < 4; ++ni)
        acc[mi][ni] = mfma16(af[mi], bf[ni], acc[mi][ni]);
    __builtin_amdgcn_s_setprio(0);
    if (st2) asm volatile("s_waitcnt vmcnt(4)" ::: "memory");   // tile t+1 resident
    else     asm volatile("s_waitcnt vmcnt(0)" ::: "memory");   // final drain
    __builtin_amdgcn_s_barrier();
  }

  // ---- epilogue ----
  __syncthreads();                      // staging LDS now reusable

  if constexpr (EPI == 1){
    if (vt && bn*128 + wn >= 1536){
      // V-column wave tile (64 rows x 64 cols, head-aligned): write vT transposed.
      u16* vbuf = sm + w*4736;          // [64][74] u16, stride 74 -> <=2-way banks
#pragma unroll
      for (int mi = 0; mi < 4; ++mi)
#pragma unroll
        for (int ni = 0; ni < 4; ++ni){
          int col = bn*128 + wn + ni*16 + lr;
          float bv = bias ? bias[col] : 0.f;
#pragma unroll
          for (int rr = 0; rr < 4; ++rr)
            vbuf[(mi*16 + lg*4 + rr)*74 + ni*16 + lr] = f2bf(acc[mi][ni][rr] + bv);
        }
      asm volatile("s_waitcnt lgkmcnt(0)" ::: "memory");
      const int row0w = bm*128 + wm;
      const int b_ = row0w >> 9, s0 = row0w & 511;
      const int h_ = (bn*128 + wn - 1536) >> 6;
#pragma unroll
      for (int e = 0; e < 8; ++e){
        int d = e*8 + (l >> 3), s8 = (l & 7)*8;
        short8 ov;
#pragma unroll
        for (int i = 0; i < 8; ++i) ov[i] = (short)vbuf[(s8 + i)*74 + d];
        *(short8*)(vt + ((u64)(b_*12 + h_)*64 + d)*512 + s0 + s8) = ov;
      }
      return;
    }
  }

  constexpr int EPLD = 68;
  float* epw = (float*)sm + w*(16*EPLD);
#pragma unroll
  for (int mi = 0; mi < 4; ++mi){
#pragma unroll
    for (int ni = 0; ni < 4; ++ni){
      int col = bn*128 + wn + ni*16 + lr;
      float bv = bias ? bias[col < N ? col : N-1] : 0.f;
#pragma unroll
      for (int rr = 0; rr < 4; ++rr){
        float v = acc[mi][ni][rr] + bv;
        if constexpr (EPI == 2) v = 0.5f*v*(1.0f + erff(v*0.70710678118f));
        epw[(lg*4 + rr)*EPLD + ni*16 + lr] = v;
      }
    }
    asm volatile("s_waitcnt lgkmcnt(0)" ::: "memory");
    if constexpr (EPI == 0){
#pragma unroll
      for (int ps = 0; ps < 4; ++ps){
        int rloc = ps*4 + (l >> 4);
        int row = bm*128 + wm + mi*16 + rloc;
        int col = bn*128 + wn + (l & 15)*4;
        f32x4 v4 = *(const f32x4*)&epw[rloc*EPLD + (l & 15)*4];
        if (row < M){
          if (col + 3 < N){
            if (xres){                     // fused post-LN residual (bf16 stream)
              ushort4 x4 = *(const ushort4*)(xres + (u64)row*N + col);
              v4[0] += bf2f(x4.x); v4[1] += bf2f(x4.y);
              v4[2] += bf2f(x4.z); v4[3] += bf2f(x4.w);
            }
            *(f32x4*)((float*)Cout + (u64)row*N + col) = v4;
          } else {
#pragma unroll
            for (int j = 0; j < 4; ++j)
              if (col + j < N){
                float vv = v4[j];
                if (xres) vv += bf2f(xres[(u64)row*N + col + j]);
                ((float*)Cout)[(u64)row*N + col + j] = vv;
              }
          }
        }
      }
    } else {
#pragma unroll
      for (int ps = 0; ps < 2; ++ps){
        int rloc = ps*8 + (l >> 3);
        int row = bm*128 + wm + mi*16 + rloc;
        int col = bn*128 + wn + (l & 7)*8;
        f32x4 a4 = *(const f32x4*)&epw[rloc*EPLD + (l & 7)*8];
        f32x4 b4 = *(const f32x4*)&epw[rloc*EPLD + (l & 7)*8 + 4];
        short8 o8;
        o8[0] = f2bf(a4[0]); o8[1] = f2bf(a4[1]); o8[2] = f2bf(a4[2]); o8[3] = f2bf(a4[3]);
        o8[4] = f2bf(b4[0]); o8[5] = f2bf(b4[1]); o8[6] = f2bf(b4[2]); o8[7] = f2bf(b4[3]);
        if (row < M){
          if (col + 7 < N) *(short8*)((u16*)Cout + (u64)row*N + col) = o8;
          else {
#pragma unroll
            for (int j = 0; j < 8; ++j)
              if (col + j < N) ((u16*)Cout)[(u64)row*N + col + j] = (u16)o8[j];
          }
        }
      }
    }
    asm volatile("s_waitcnt lgkmcnt(0)" ::: "memory");
  }
}

// ---------------------------------------------------------------- 256x256 8-wave GEMM (vocab, fused row-gather)
DEV void stage_tile(const u16* __restrict__ X, int ld, int limit,
                    int rowbase, int k0, u16* lds, int t)
{
  const int rl  = t >> 2;
  const int col = (((t & 3) ^ ((t >> 3) & 3))) << 3;
  int r0 = rowbase + rl;        if (r0 > limit-1) r0 = limit-1;
  int r1 = rowbase + rl + 128;  if (r1 > limit-1) r1 = limit-1;
  async16(X + (u64)r0*ld + k0 + col, lds + t*8);
  async16(X + (u64)r1*ld + k0 + col, lds + 4096 + t*8);
}

__global__ __launch_bounds__(512)
void gemm8v(const u16* __restrict__ xb, const int* __restrict__ mids,
            const u16* __restrict__ W,
            const float* __restrict__ bias, float* __restrict__ Cout,
            int M, int N, int K, int GM)
{
  __shared__ u16 sm[49152];
  u16* Ab = sm;
  u16* Bb = sm + 24576;
  const int t = threadIdx.x;
  const int w = t >> 6, l = t & 63;
  const int lr = l & 15, lg = l >> 4;
  const int wr = w >> 2, wc = w & 3;
  const int xr = (lr >> 1) & 3;
  const int slot = lg ^ xr;

  const int nwg = gridDim.x, orig = blockIdx.x;
  const int q = nwg >> 3, r = nwg & 7;
  const int xcd = orig & 7, sl8 = orig >> 3;
  const int wgid = (xcd < r ? xcd*(q+1) : r*(q+1) + (xcd-r)*q) + sl8;
  const int bm = wgid % GM, bn = wgid / GM;

  // A rows gathered through mask_ids: logical row r -> xb row (r/77)*512 + mids[r]
  const int rl_ = t >> 2;
  const int colsw = (((t & 3) ^ ((t >> 3) & 3))) << 3;
  int r0 = bm*256 + rl_;        if (r0 > M-1) r0 = M-1;
  int r1 = bm*256 + rl_ + 128;  if (r1 > M-1) r1 = M-1;
  const int g0 = (r0/77)*512 + mids[r0];
  const int g1 = (r1/77)*512 + mids[r1];
  const u16* pa0 = xb + (u64)g0*768 + colsw;
  const u16* pa1 = xb + (u64)g1*768 + colsw;

  f32x4 acc[8][4] = {};
  short8 afr[4], bfr[4];

  const int NT = K >> 5;
  async16(pa0, Ab + t*8); async16(pa1, Ab + 4096 + t*8);
  stage_tile(W, K, N, bn*256,  0, Bb,        t);
  async16(pa0 + 32, Ab + 8192 + t*8); async16(pa1 + 32, Ab + 12288 + t*8);
  stage_tile(W, K, N, bn*256, 32, Bb + 8192, t);
  asm volatile("s_waitcnt vmcnt(4)" ::: "memory");
  __builtin_amdgcn_s_barrier();

  for (int tt = 0; tt < NT; ++tt){
    const int rs = (tt % 3) * 8192;
    const int rs2 = ((tt + 2) % 3) * 8192;
    const int k2 = (tt + 2)*32;
    const u16* Ar = Ab + rs;
    const u16* Br = Bb + rs;
#pragma unroll
    for (int mi = 0; mi < 4; ++mi) afr[mi] = ldfrag(Ar, wr*128 + mi*16 + lr, slot);
#pragma unroll
    for (int ni = 0; ni < 4; ++ni) bfr[ni] = ldfrag(Br, wc*64 + ni*16 + lr, slot);
    if (tt + 2 < NT){
      async16(pa0 + k2, Ab + rs2 + t*8);
      async16(pa1 + k2, Ab + rs2 + 4096 + t*8);
    }
    __builtin_amdgcn_s_barrier();
    __builtin_amdgcn_s_setprio(1);
#pragma unroll
    for (int mi = 0; mi < 4; ++mi)
#pragma unroll
      for (int ni = 0; ni < 4; ++ni)
        acc[mi][ni] = mfma16(afr[mi], bfr[ni], acc[mi][ni]);
    __builtin_amdgcn_s_setprio(0);
    __builtin_amdgcn_s_barrier();
#pragma unroll
    for (int mi = 0; mi < 4; ++mi) afr[mi] = ldfrag(Ar, wr*128 + (mi+4)*16 + lr, slot);
    if (tt + 2 < NT) stage_tile(W, K, N, bn*256, k2, Bb + rs2, t);
    __builtin_amdgcn_s_barrier();
    __builtin_amdgcn_s_setprio(1);
#pragma unroll
    for (int mi = 0; mi < 4; ++mi)
#pragma unroll
      for (int ni = 0; ni < 4; ++ni)
        acc[mi+4][ni] = mfma16(afr[mi], bfr[ni], acc[mi+4][ni]);
    __builtin_amdgcn_s_setprio(0);
    if (tt + 2 < NT) asm volatile("s_waitcnt vmcnt(4)" ::: "memory");
    else             asm volatile("s_waitcnt vmcnt(0)" ::: "memory");
    __builtin_amdgcn_s_barrier();
  }

  __syncthreads();
  constexpr int EPLD = 68;
  float* epw = (float*)sm + w*(16*EPLD);
  const int growbase = bm*256 + wr*128;
  const int gcolbase = bn*256 + wc*64;
#pragma unroll
  for (int mi = 0; mi < 8; ++mi){
#pragma unroll
    for (int ni = 0; ni < 4; ++ni){
      int col = gcolbase + ni*16 + lr;
      float bv = bias ? bias[col < N ? col : N-1] : 0.f;
#pragma unroll
      for (int rr = 0; rr < 4; ++rr)
        epw[(lg*4 + rr)*EPLD + ni*16 + lr] = acc[mi][ni][rr] + bv;
    }
    asm volatile("s_waitcnt lgkmcnt(0)" ::: "memory");
#pragma unroll
    for (int ps = 0; ps < 4; ++ps){
      int rloc = ps*4 + (l >> 4);
      int row = growbase + mi*16 + rloc;
      int col = gcolbase + (l & 15)*4;
      f32x4 v4 = *(const f32x4*)&epw[rloc*EPLD + (l & 15)*4];
      if (row < M){
        if (col + 3 < N) *(f32x4*)(Cout + (u64)row*N + col) = v4;
        else {
#pragma unroll
          for (int j = 0; j < 4; ++j)
            if (col + j < N) Cout[(u64)row*N + col + j] = v4[j];
        }
      }
    }
    asm volatile("s_waitcnt lgkmcnt(0)" ::: "memory");
  }
}

// ---------------------------------------------------------------- flash attention, no-max softmax, 32 q-rows/wave
__global__ __launch_bounds__(256)
void attn_kernel(const u16* __restrict__ qkv, const u16* __restrict__ vt,
                 u16* __restrict__ ob)
{
  __shared__ u16 p_lds[4][32][72];
  const int t = threadIdx.x, w = t >> 6, ll = t & 63;
  const int lr = ll & 15, lg = ll >> 4;
  const int qt = blockIdx.x, h = blockIdx.y, b = blockIdx.z;
  const int q0 = qt*128 + w*32;
  const float C = 0.125f * 1.44269504f;   // 1/sqrt(64) * log2(e)

  short8 qf[2][2];
#pragma unroll
  for (int f = 0; f < 2; ++f){
    const u16* qrow = qkv + (u64)(b*512 + q0 + f*16 + lr)*2304 + h*64 + 8*lg;
    qf[f][0] = *(const short8*)qrow;
    qf[f][1] = *(const short8*)(qrow + 32);
  }

  const u16* kbh = qkv + (u64)(b*512)*2304 + 768 + h*64;
  const u16* vth = vt + (u64)(b*12 + h)*64*512;

  f32x4 lacc[2] = {};
  f32x4 o_acc[2][4] = {};

  for (int jt = 0; jt < 8; ++jt){
    const int jb = jt*64;
    f32x4 s[2][4] = {};
#pragma unroll
    for (int jn = 0; jn < 4; ++jn){
      const u16* kr = kbh + (u64)(jb + jn*16 + lr)*2304 + 8*lg;
      short8 kf0 = *(const short8*)kr;
      short8 kf1 = *(const short8*)(kr + 32);
#pragma unroll
      for (int f = 0; f < 2; ++f){
        s[f][jn] = mfma16(qf[f][0], kf0, s[f][jn]);
        s[f][jn] = mfma16(qf[f][1], kf1, s[f][jn]);
      }
    }
#pragma unroll
    for (int f = 0; f < 2; ++f)
#pragma unroll
      for (int jn = 0; jn < 4; ++jn)
#pragma unroll
        for (int r = 0; r < 4; ++r){
          float pv = exp2f(s[f][jn][r]*C);
          lacc[f][r] += pv;
          p_lds[w][f*16 + 4*lg + r][jn*16 + lr] = f2bf(pv);
        }
    // per-wave LDS region: wave-local wait suffices (DS pipe in-order per wave)
    asm volatile("s_waitcnt lgkmcnt(0)" ::: "memory");
    short8 pa[2][2];
#pragma unroll
    for (int f = 0; f < 2; ++f){
      pa[f][0] = *(const short8*)(&p_lds[w][f*16 + lr][8*lg]);
      pa[f][1] = *(const short8*)(&p_lds[w][f*16 + lr][32 + 8*lg]);
    }
#pragma unroll
    for (int nd = 0; nd < 4; ++nd){
      const u16* vr = vth + (u64)(nd*16 + lr)*512 + jb + 8*lg;
      short8 vf0 = *(const short8*)vr;
      short8 vf1 = *(const short8*)(vr + 32);
#pragma unroll
      for (int f = 0; f < 2; ++f){
        o_acc[f][nd] = mfma16(pa[f][0], vf0, o_acc[f][nd]);
        o_acc[f][nd] = mfma16(pa[f][1], vf1, o_acc[f][nd]);
      }
    }
    asm volatile("s_waitcnt lgkmcnt(0)" ::: "memory");
  }
  float l_r[2][4];
#pragma unroll
  for (int f = 0; f < 2; ++f)
#pragma unroll
    for (int r = 0; r < 4; ++r){
      float v = lacc[f][r];
#pragma unroll
      for (int m = 1; m < 16; m <<= 1) v += __shfl_xor(v, m);
      l_r[f][r] = 1.f / v;
    }
#pragma unroll
  for (int f = 0; f < 2; ++f)
#pragma unroll
    for (int nd = 0; nd < 4; ++nd)
#pragma unroll
      for (int r = 0; r < 4; ++r)
        p_lds[w][f*16 + 4*lg + r][nd*16 + lr] = f2bf(o_acc[f][nd][r]*l_r[f][r]);
  asm volatile("s_waitcnt lgkmcnt(0)" ::: "memory");
#pragma unroll
  for (int ps = 0; ps < 4; ++ps){
    int row = ps*8 + (ll >> 3);
    short8 ov = *(const short8*)(&p_lds[w][row][(ll & 7)*8]);
    *(short8*)(ob + (u64)(b*512 + q0 + row)*768 + h*64 + (ll & 7)*8) = ov;
  }
}

// ---------------------------------------------------------------- host
extern "C" void kernel_launch(void* const* d_in, const int* in_sizes, int n_in,
                              void* d_out, int out_size, void* d_ws, size_t ws_size,
                              hipStream_t stream)
{
  const int*   token_ids  = (const int*)  d_in[0];
  const int*   segment_ids= (const int*)  d_in[1];
  const int*   mask_ids   = (const int*)  d_in[2];
  const float* tok_emb    = (const float*)d_in[3];
  const float* pos_emb    = (const float*)d_in[4];
  const float* seg_emb    = (const float*)d_in[5];
  const float* dense_w    = (const float*)d_in[6];
  const float* dense_b    = (const float*)d_in[7];
  const float* Wq = (const float*)d_in[8];  const float* bq = (const float*)d_in[9];
  const float* Wk = (const float*)d_in[10]; const float* bk = (const float*)d_in[11];
  const float* Wv = (const float*)d_in[12]; const float* bv = (const float*)d_in[13];
  const float* Wo = (const float*)d_in[14]; const float* bo = (const float*)d_in[15];
  const float* W1 = (const float*)d_in[16]; const float* b1 = (const float*)d_in[17];
  const float* W2 = (const float*)d_in[18]; const float* b2 = (const float*)d_in[19];
  const float* g1 = (const float*)d_in[20]; const float* be1= (const float*)d_in[21];
  const float* g2 = (const float*)d_in[22]; const float* be2= (const float*)d_in[23];

  char* p = (char*)d_ws;
  auto alloc = [&](size_t bytes)->char*{
    char* r = p; p += (bytes + 255) & ~(size_t)255; return r;
  };
  const u64 T = 8192;
  float* y    = (float*)alloc(T*768*4);   // fp32 GEMM+residual scratch
  u16*   xb   = (u16*)  alloc(T*768*2);   // bf16 post-LN residual stream
  u16*   qkvb = (u16*)  alloc(T*2304*2);  // Q,K parts (V goes straight to vT)
  u16*   vT   = (u16*)  alloc(T*768*2);
  u16*   obuf = (u16*)  alloc(T*768*2);
  u16*   h1b  = (u16*)  alloc(T*3072*2);
  u16*   wqkv = (u16*)  alloc((u64)2304*768*2);
  u16*   wob  = (u16*)  alloc((u64)768*768*2);
  u16*   w1b  = (u16*)  alloc((u64)3072*768*2);
  u16*   w2b  = (u16*)  alloc((u64)3072*768*2);
  float* bqkv = (float*)alloc((u64)12*2304*4);
  u16*   dwb  = h1b;   // reuse (dense_w bf16 = 46.9 MB <= h1b 50.3 MB)

  if ((size_t)(p - (char*)d_ws) > ws_size) return;

  embed_kernel<<<dim3(8192), dim3(256), 0, stream>>>(
      token_ids, segment_ids, tok_emb, pos_emb, seg_emb, xb);
  concat_bias<<<dim3(12), dim3(256), 0, stream>>>(bq, bk, bv, bqkv);
  cvt_layer<<<dim3(6912), dim3(256), 0, stream>>>(
      (const float4*)Wq, (const float4*)Wk, (const float4*)Wv, (const float4*)Wo,
      (const float4*)W1, (const float4*)W2,
      (ushort4*)wqkv, (ushort4*)wob, (ushort4*)w1b, (ushort4*)w2b);

  for (int l = 0; l < 12; ++l){
    // QKV: [8192,768] @ [2304,768]^T -> Q,K to qkvb; V transposed to vT in-epilogue
    gemm3r<1><<<dim3(64*18), dim3(256), 0, stream>>>(xb, wqkv, bqkv + (u64)l*2304, nullptr,
                                                     vT, qkvb, 8192, 2304, 768, 64);

    attn_kernel<<<dim3(4, 12, 16), dim3(256), 0, stream>>>(qkvb, vT, obuf);

    // o-proj + residual: y = obuf@Wo^T + bo + bf2f(xb)
    gemm3r<0><<<dim3(64*6), dim3(256), 0, stream>>>(obuf, wob, bo + (u64)l*768, xb,
                                                    nullptr, y, 8192, 768, 768, 64);
    ln_wave<<<dim3(2048), dim3(256), 0, stream>>>(y, g1 + (u64)l*768, be1 + (u64)l*768, xb);

    // FFN1: [8192,768] @ [3072,768]^T -> bf16 + GELU
    gemm3r<2><<<dim3(64*24), dim3(256), 0, stream>>>(xb, w1b, b1 + (u64)l*3072, nullptr,
                                                     nullptr, h1b, 8192, 3072, 768, 64);
    // FFN2 + residual: y = h1b@W2^T + b2 + bf2f(xb)
    gemm3r<0><<<dim3(64*6), dim3(256), 0, stream>>>(h1b, w2b, b2 + (u64)l*768, xb,
                                                    nullptr, y, 8192, 768, 3072, 64);
    if (l < 11){
      // fused: ln2(l) + weight conversion for layer l+1
      ln2cvt<<<dim3(2048 + 6912), dim3(256), 0, stream>>>(
          y, g2 + (u64)l*768, be2 + (u64)l*768, xb,
          (const float4*)(Wq + (u64)(l+1)*589824), (const float4*)(Wk + (u64)(l+1)*589824),
          (const float4*)(Wv + (u64)(l+1)*589824), (const float4*)(Wo + (u64)(l+1)*589824),
          (const float4*)(W1 + (u64)(l+1)*2359296), (const float4*)(W2 + (u64)(l+1)*2359296),
          (ushort4*)wqkv, (ushort4*)wob, (ushort4*)w1b, (ushort4*)w2b);
    } else {
      ln_wave<<<dim3(2048), dim3(256), 0, stream>>>(y, g2 + (u64)l*768, be2 + (u64)l*768, xb);
    }
  }

  cvt_bf16<<<dim3(22892), dim3(256), 0, stream>>>((const float4*)dense_w, (ushort4*)dwb, 5860224);
  // vocab: gathers masked rows from xb directly via mask_ids
  gemm8v<<<dim3(5*120), dim3(512), 0, stream>>>(xb, mask_ids, dwb, dense_b, (float*)d_out,
                                                1232, 30522, 768, 5);
}

// Round 15
// 3529.200 us; speedup vs baseline: 1.1400x; 1.0225x over previous
//
#include <hip/hip_runtime.h>
#include <stdint.h>

typedef uint16_t u16;
typedef uint32_t u32;
typedef uint64_t u64;
typedef short short8 __attribute__((ext_vector_type(8)));
typedef float f32x4 __attribute__((ext_vector_type(4)));

#define DEV static __device__ __forceinline__

DEV u16 f2bf(float f){
  u32 x = __builtin_bit_cast(u32, f);
  return (u16)((x + 0x7fffu + ((x >> 16) & 1u)) >> 16);
}

DEV float bf2f(u16 u){
  u32 v = (u32)u << 16;
  return __builtin_bit_cast(float, v);
}

DEV f32x4 mfma16(short8 a, short8 b, f32x4 c){
  return __builtin_amdgcn_mfma_f32_16x16x32_bf16(a, b, c, 0, 0, 0);
}

DEV void async16(const void* g, void* l){
  __builtin_amdgcn_global_load_lds(
      (const __attribute__((address_space(1))) u32*)g,
      (__attribute__((address_space(3))) u32*)l, 16, 0, 0);
}

// ---------------------------------------------------------------- embedding (bf16 only; xb IS the residual stream)
__global__ __launch_bounds__(256)
void embed_kernel(const int* __restrict__ tid, const int* __restrict__ sid,
                  const float* __restrict__ tok, const float* __restrict__ pos,
                  const float* __restrict__ seg, u16* __restrict__ xb)
{
  const int row = blockIdx.x;          // b*512 + s
  const int s = row & 511;
  const int tk = tid[row], sg = sid[row];
  const int t = threadIdx.x;
#pragma unroll
  for (int e = 0; e < 3; ++e){
    int i = t + e*256;
    float v = tok[(u64)tk*768 + i] + seg[(u64)sg*768 + i] + pos[(u64)s*768 + i];
    xb[(u64)row*768 + i] = f2bf(v);
  }
}

// ---------------------------------------------------------------- fp32 -> bf16 (dense_w)
__global__ __launch_bounds__(256)
void cvt_bf16(const float4* __restrict__ in, ushort4* __restrict__ out, int n4)
{
  int i = blockIdx.x*256 + threadIdx.x;
  if (i >= n4) return;
  float4 f = in[i];
  ushort4 o;
  o.x = f2bf(f.x); o.y = f2bf(f.y); o.z = f2bf(f.z); o.w = f2bf(f.w);
  out[i] = o;
}

// ---------------------------------------------------------------- per-layer weight conversion core
DEV void cvt_body(int i,
                  const float4* __restrict__ Wq, const float4* __restrict__ Wk,
                  const float4* __restrict__ Wv, const float4* __restrict__ Wo,
                  const float4* __restrict__ W1, const float4* __restrict__ W2,
                  ushort4* __restrict__ wqkv, ushort4* __restrict__ wob,
                  ushort4* __restrict__ w1b, ushort4* __restrict__ w2b)
{
  const int S = 147456;                         // 768*768/4
  float4 f; ushort4* dst; int di;
  if      (i <   S)       { f = Wq[i];            dst = wqkv; di = i; }
  else if (i < 2*S)       { f = Wk[i - S];        dst = wqkv; di = i; }
  else if (i < 3*S)       { f = Wv[i - 2*S];      dst = wqkv; di = i; }
  else if (i < 4*S)       { f = Wo[i - 3*S];      dst = wob;  di = i - 3*S; }
  else if (i < 4*S+589824){ f = W1[i - 4*S];      dst = w1b;  di = i - 4*S; }
  else                    { f = W2[i - 4*S-589824]; dst = w2b; di = i - 4*S - 589824; }
  ushort4 o;
  o.x = f2bf(f.x); o.y = f2bf(f.y); o.z = f2bf(f.z); o.w = f2bf(f.w);
  dst[di] = o;
}

__global__ __launch_bounds__(256)
void cvt_layer(const float4* __restrict__ Wq, const float4* __restrict__ Wk,
               const float4* __restrict__ Wv, const float4* __restrict__ Wo,
               const float4* __restrict__ W1, const float4* __restrict__ W2,
               ushort4* __restrict__ wqkv, ushort4* __restrict__ wob,
               ushort4* __restrict__ w1b, ushort4* __restrict__ w2b)
{
  cvt_body(blockIdx.x*256 + threadIdx.x, Wq, Wk, Wv, Wo, W1, W2, wqkv, wob, w1b, w2b);
}

// ---------------------------------------------------------------- bias concat (Q,K,V)
__global__ __launch_bounds__(256)
void concat_bias(const float* __restrict__ bq, const float* __restrict__ bk,
                 const float* __restrict__ bv, float* __restrict__ out)
{
  const int l = blockIdx.x;
  const int t = threadIdx.x;
#pragma unroll
  for (int e = 0; e < 3; ++e){
    int i = t + e*256;
    out[(u64)l*2304 + i]        = bq[(u64)l*768 + i];
    out[(u64)l*2304 + 768 + i]  = bk[(u64)l*768 + i];
    out[(u64)l*2304 + 1536 + i] = bv[(u64)l*768 + i];
  }
}

// ---------------------------------------------------------------- LayerNorm core: one wave per row, bf16 y input
DEV void ln_row(const u16* __restrict__ yr, const float* __restrict__ g,
                const float* __restrict__ be, u16* __restrict__ xr, int ll)
{
  float v[12]; float s = 0.f, sq = 0.f;
#pragma unroll
  for (int e = 0; e < 3; ++e){
    ushort4 u4 = *(const ushort4*)(yr + e*256 + ll*4);
    v[e*4+0] = bf2f(u4.x); v[e*4+1] = bf2f(u4.y);
    v[e*4+2] = bf2f(u4.z); v[e*4+3] = bf2f(u4.w);
#pragma unroll
    for (int j = 0; j < 4; ++j){ s += v[e*4+j]; sq += v[e*4+j]*v[e*4+j]; }
  }
#pragma unroll
  for (int m = 1; m < 64; m <<= 1){ s += __shfl_xor(s, m); sq += __shfl_xor(sq, m); }
  const float mean = s*(1.f/768.f);
  const float rstd = rsqrtf(sq*(1.f/768.f) - mean*mean + 1e-5f);
#pragma unroll
  for (int e = 0; e < 3; ++e){
    f32x4 gv = *(const f32x4*)(g  + e*256 + ll*4);
    f32x4 bv = *(const f32x4*)(be + e*256 + ll*4);
    ushort4 o;
    o.x = f2bf((v[e*4+0] - mean)*rstd*gv[0] + bv[0]);
    o.y = f2bf((v[e*4+1] - mean)*rstd*gv[1] + bv[1]);
    o.z = f2bf((v[e*4+2] - mean)*rstd*gv[2] + bv[2]);
    o.w = f2bf((v[e*4+3] - mean)*rstd*gv[3] + bv[3]);
    *(ushort4*)(xr + e*256 + ll*4) = o;
  }
}

__global__ __launch_bounds__(256)
void ln_wave(const u16* __restrict__ yin, const float* __restrict__ g,
             const float* __restrict__ be, u16* __restrict__ xbout)
{
  const int t = threadIdx.x, w = t >> 6, ll = t & 63;
  const u64 row = (u64)blockIdx.x*4 + w;
  ln_row(yin + row*768, g, be, xbout + row*768, ll);
}

// fused: blocks [0,2048) do LN; blocks [2048, 2048+6912) convert next layer's weights
__global__ __launch_bounds__(256)
void ln2cvt(const u16* __restrict__ yin, const float* __restrict__ g,
            const float* __restrict__ be, u16* __restrict__ xbout,
            const float4* __restrict__ Wq, const float4* __restrict__ Wk,
            const float4* __restrict__ Wv, const float4* __restrict__ Wo,
            const float4* __restrict__ W1, const float4* __restrict__ W2,
            ushort4* __restrict__ wqkv, ushort4* __restrict__ wob,
            ushort4* __restrict__ w1b, ushort4* __restrict__ w2b)
{
  if (blockIdx.x < 2048){
    const int t = threadIdx.x, w = t >> 6, ll = t & 63;
    const u64 row = (u64)blockIdx.x*4 + w;
    ln_row(yin + row*768, g, be, xbout + row*768, ll);
  } else {
    cvt_body((blockIdx.x - 2048)*256 + threadIdx.x,
             Wq, Wk, Wv, Wo, W1, W2, wqkv, wob, w1b, w2b);
  }
}

// ================================================================ 128x128 ring-3 GEMM
// EPI 0: bf16 store with fused residual add from bf16 xres (pre-LN sum, bf16-rounded).
// EPI 1: bf16 store; V-column blocks (col>=1536, vt!=null) write transposed vT directly.
// EPI 2: bf16 store + exact GELU.
DEV void stage128(const u16* __restrict__ X, int ld, int limit,
                  int rowbase, int k0, u16* lds, int t)
{
  const int rl  = t >> 2;                             // 0..63
  const int col = (((t & 3) ^ ((t >> 3) & 3))) << 3;  // pre-swizzled source col
  int r0 = rowbase + rl;       if (r0 > limit-1) r0 = limit-1;
  int r1 = rowbase + rl + 64;  if (r1 > limit-1) r1 = limit-1;
  async16(X + (u64)r0*ld + k0 + col, lds + t*8);
  async16(X + (u64)r1*ld + k0 + col, lds + 2048 + t*8);
}

DEV short8 ldfrag(const u16* buf, int row, int slot){
  return *(const short8*)(buf + row*32 + (slot << 3));
}

template<int EPI>
__global__ __launch_bounds__(256)
void gemm3r(const u16* __restrict__ A, const u16* __restrict__ W,
            const float* __restrict__ bias, const u16* __restrict__ xres,
            u16* __restrict__ vt, void* __restrict__ Cout,
            int M, int N, int K, int GM)
{
  __shared__ u16 sm[24576];     // 48 KB
  const int t = threadIdx.x;
  const int w = t >> 6, l = t & 63;
  const int lr = l & 15, lg = l >> 4;
  const int wm = (w >> 1)*64, wn = (w & 1)*64;
  const int xr = (lr >> 1) & 3;
  const int slot = lg ^ xr;

  // bijective chunked XCD swizzle (m204), bm-fast
  const int nwg = gridDim.x, orig = blockIdx.x;
  const int q = nwg >> 3, r = nwg & 7;
  const int xcd = orig & 7, sl8 = orig >> 3;
  const int wgid = (xcd < r ? xcd*(q+1) : r*(q+1) + (xcd-r)*q) + sl8;
  const int bm = wgid % GM, bn = wgid / GM;

  f32x4 acc[4][4] = {};
  short8 af[4], bf[4];

  const int NT = K >> 5;
  // prologue: stage tiles 0,1
  stage128(A, K, M, bm*128,  0, sm,          t);
  stage128(W, K, N, bn*128,  0, sm + 4096,   t);
  stage128(A, K, M, bm*128, 32, sm + 8192,   t);
  stage128(W, K, N, bn*128, 32, sm + 12288,  t);
  asm volatile("s_waitcnt vmcnt(4)" ::: "memory");
  __builtin_amdgcn_s_barrier();

  for (int tt = 0; tt < NT; ++tt){
    const int rs  = (tt % 3) * 8192;
    const int rs2 = ((tt + 2) % 3) * 8192;
    const int k2  = (tt + 2) * 32;
    const bool st2 = (tt + 2) < NT;
    const u16* Ar = sm + rs;
    const u16* Br = sm + rs + 4096;

    // ---- phase A: read A mi0-1 + all B ; stage A(t+2) ; MFMA (mi0-1 x ni0-3) ----
    af[0] = ldfrag(Ar, wm + lr, slot);
    af[1] = ldfrag(Ar, wm + 16 + lr, slot);
#pragma unroll
    for (int ni = 0; ni < 4; ++ni) bf[ni] = ldfrag(Br, wn + ni*16 + lr, slot);
    if (st2) stage128(A, K, M, bm*128, k2, sm + rs2, t);
    __builtin_amdgcn_s_barrier();
    __builtin_amdgcn_s_setprio(1);
#pragma unroll
    for (int mi = 0; mi < 2; ++mi)
#pragma unroll
      for (int ni = 0; ni < 4; ++ni)
        acc[mi][ni] = mfma16(af[mi], bf[ni], acc[mi][ni]);
    __builtin_amdgcn_s_setprio(0);
    __builtin_amdgcn_s_barrier();

    // ---- phase B: read A mi2-3 ; stage B(t+2) ; MFMA (mi2-3 x ni0-3) ----
    af[2] = ldfrag(Ar, wm + 32 + lr, slot);
    af[3] = ldfrag(Ar, wm + 48 + lr, slot);
    if (st2) stage128(W, K, N, bn*128, k2, sm + rs2 + 4096, t);
    __builtin_amdgcn_s_barrier();
    __builtin_amdgcn_s_setprio(1);
#pragma unroll
    for (int mi = 2; mi < 4; ++mi)
#pragma unroll
      for (int ni = 0; ni < 4; ++ni)
        acc[mi][ni] = mfma16(af[mi], bf[ni], acc[mi][ni]);
    __builtin_amdgcn_s_setprio(0);
    if (st2) asm volatile("s_waitcnt vmcnt(4)" ::: "memory");   // tile t+1 resident
    else     asm volatile("s_waitcnt vmcnt(0)" ::: "memory");   // final drain
    __builtin_amdgcn_s_barrier();
  }

  // ---- epilogue ----
  __syncthreads();                      // staging LDS now reusable

  if constexpr (EPI == 1){
    if (vt && bn*128 + wn >= 1536){
      // V-column wave tile (64 rows x 64 cols, head-aligned): write vT transposed.
      u16* vbuf = sm + w*4736;          // [64][74] u16, stride 74 -> <=2-way banks
#pragma unroll
      for (int mi = 0; mi < 4; ++mi)
#pragma unroll
        for (int ni = 0; ni < 4; ++ni){
          int col = bn*128 + wn + ni*16 + lr;
          float bv = bias ? bias[col] : 0.f;
#pragma unroll
          for (int rr = 0; rr < 4; ++rr)
            vbuf[(mi*16 + lg*4 + rr)*74 + ni*16 + lr] = f2bf(acc[mi][ni][rr] + bv);
        }
      asm volatile("s_waitcnt lgkmcnt(0)" ::: "memory");
      const int row0w = bm*128 + wm;
      const int b_ = row0w >> 9, s0 = row0w & 511;
      const int h_ = (bn*128 + wn - 1536) >> 6;
#pragma unroll
      for (int e = 0; e < 8; ++e){
        int d = e*8 + (l >> 3), s8 = (l & 7)*8;
        short8 ov;
#pragma unroll
        for (int i = 0; i < 8; ++i) ov[i] = (short)vbuf[(s8 + i)*74 + d];
        *(short8*)(vt + ((u64)(b_*12 + h_)*64 + d)*512 + s0 + s8) = ov;
      }
      return;
    }
  }

  constexpr int EPLD = 68;
  float* epw = (float*)sm + w*(16*EPLD);
#pragma unroll
  for (int mi = 0; mi < 4; ++mi){
#pragma unroll
    for (int ni = 0; ni < 4; ++ni){
      int col = bn*128 + wn + ni*16 + lr;
      float bv = bias ? bias[col < N ? col : N-1] : 0.f;
#pragma unroll
      for (int rr = 0; rr < 4; ++rr){
        float v = acc[mi][ni][rr] + bv;
        if constexpr (EPI == 2) v = 0.5f*v*(1.0f + erff(v*0.70710678118f));
        epw[(lg*4 + rr)*EPLD + ni*16 + lr] = v;
      }
    }
    asm volatile("s_waitcnt lgkmcnt(0)" ::: "memory");
    // bf16 store path (all EPI): EPI 0 adds bf16 residual before rounding
#pragma unroll
    for (int ps = 0; ps < 2; ++ps){
      int rloc = ps*8 + (l >> 3);
      int row = bm*128 + wm + mi*16 + rloc;
      int col = bn*128 + wn + (l & 7)*8;
      f32x4 a4 = *(const f32x4*)&epw[rloc*EPLD + (l & 7)*8];
      f32x4 b4 = *(const f32x4*)&epw[rloc*EPLD + (l & 7)*8 + 4];
      if (row < M){
        if constexpr (EPI == 0){
          if (xres && col + 7 < N){
            short8 x8 = *(const short8*)(xres + (u64)row*N + col);
            a4[0] += bf2f((u16)x8[0]); a4[1] += bf2f((u16)x8[1]);
            a4[2] += bf2f((u16)x8[2]); a4[3] += bf2f((u16)x8[3]);
            b4[0] += bf2f((u16)x8[4]); b4[1] += bf2f((u16)x8[5]);
            b4[2] += bf2f((u16)x8[6]); b4[3] += bf2f((u16)x8[7]);
          }
        }
        short8 o8;
        o8[0] = f2bf(a4[0]); o8[1] = f2bf(a4[1]); o8[2] = f2bf(a4[2]); o8[3] = f2bf(a4[3]);
        o8[4] = f2bf(b4[0]); o8[5] = f2bf(b4[1]); o8[6] = f2bf(b4[2]); o8[7] = f2bf(b4[3]);
        if (col + 7 < N) *(short8*)((u16*)Cout + (u64)row*N + col) = o8;
        else {
#pragma unroll
          for (int j = 0; j < 8; ++j)
            if (col + j < N) ((u16*)Cout)[(u64)row*N + col + j] = (u16)o8[j];
        }
      }
    }
    asm volatile("s_waitcnt lgkmcnt(0)" ::: "memory");  // epw reads done before next mi
  }
}

// ---------------------------------------------------------------- 256x256 8-wave GEMM (vocab, fused row-gather)
DEV void stage_tile(const u16* __restrict__ X, int ld, int limit,
                    int rowbase, int k0, u16* lds, int t)
{
  const int rl  = t >> 2;
  const int col = (((t & 3) ^ ((t >> 3) & 3))) << 3;
  int r0 = rowbase + rl;        if (r0 > limit-1) r0 = limit-1;
  int r1 = rowbase + rl + 128;  if (r1 > limit-1) r1 = limit-1;
  async16(X + (u64)r0*ld + k0 + col, lds + t*8);
  async16(X + (u64)r1*ld + k0 + col, lds + 4096 + t*8);
}

__global__ __launch_bounds__(512)
void gemm8v(const u16* __restrict__ xb, const int* __restrict__ mids,
            const u16* __restrict__ W,
            const float* __restrict__ bias, float* __restrict__ Cout,
            int M, int N, int K, int GM)
{
  __shared__ u16 sm[49152];
  u16* Ab = sm;
  u16* Bb = sm + 24576;
  const int t = threadIdx.x;
  const int w = t >> 6, l = t & 63;
  const int lr = l & 15, lg = l >> 4;
  const int wr = w >> 2, wc = w & 3;
  const int xr = (lr >> 1) & 3;
  const int slot = lg ^ xr;

  const int nwg = gridDim.x, orig = blockIdx.x;
  const int q = nwg >> 3, r = nwg & 7;
  const int xcd = orig & 7, sl8 = orig >> 3;
  const int wgid = (xcd < r ? xcd*(q+1) : r*(q+1) + (xcd-r)*q) + sl8;
  const int bm = wgid % GM, bn = wgid / GM;

  // A rows gathered through mask_ids: logical row r -> xb row (r/77)*512 + mids[r]
  const int rl_ = t >> 2;
  const int colsw = (((t & 3) ^ ((t >> 3) & 3))) << 3;
  int r0 = bm*256 + rl_;        if (r0 > M-1) r0 = M-1;
  int r1 = bm*256 + rl_ + 128;  if (r1 > M-1) r1 = M-1;
  const int g0 = (r0/77)*512 + mids[r0];
  const int g1 = (r1/77)*512 + mids[r1];
  const u16* pa0 = xb + (u64)g0*768 + colsw;
  const u16* pa1 = xb + (u64)g1*768 + colsw;

  f32x4 acc[8][4] = {};
  short8 afr[4], bfr[4];

  const int NT = K >> 5;
  async16(pa0, Ab + t*8); async16(pa1, Ab + 4096 + t*8);
  stage_tile(W, K, N, bn*256,  0, Bb,        t);
  async16(pa0 + 32, Ab + 8192 + t*8); async16(pa1 + 32, Ab + 12288 + t*8);
  stage_tile(W, K, N, bn*256, 32, Bb + 8192, t);
  asm volatile("s_waitcnt vmcnt(4)" ::: "memory");
  __builtin_amdgcn_s_barrier();

  for (int tt = 0; tt < NT; ++tt){
    const int rs = (tt % 3) * 8192;
    const int rs2 = ((tt + 2) % 3) * 8192;
    const int k2 = (tt + 2)*32;
    const u16* Ar = Ab + rs;
    const u16* Br = Bb + rs;
#pragma unroll
    for (int mi = 0; mi < 4; ++mi) afr[mi] = ldfrag(Ar, wr*128 + mi*16 + lr, slot);
#pragma unroll
    for (int ni = 0; ni < 4; ++ni) bfr[ni] = ldfrag(Br, wc*64 + ni*16 + lr, slot);
    if (tt + 2 < NT){
      async16(pa0 + k2, Ab + rs2 + t*8);
      async16(pa1 + k2, Ab + rs2 + 4096 + t*8);
    }
    __builtin_amdgcn_s_barrier();
    __builtin_amdgcn_s_setprio(1);
#pragma unroll
    for (int mi = 0; mi < 4; ++mi)
#pragma unroll
      for (int ni = 0; ni < 4; ++ni)
        acc[mi][ni] = mfma16(afr[mi], bfr[ni], acc[mi][ni]);
    __builtin_amdgcn_s_setprio(0);
    __builtin_amdgcn_s_barrier();
#pragma unroll
    for (int mi = 0; mi < 4; ++mi) afr[mi] = ldfrag(Ar, wr*128 + (mi+4)*16 + lr, slot);
    if (tt + 2 < NT) stage_tile(W, K, N, bn*256, k2, Bb + rs2, t);
    __builtin_amdgcn_s_barrier();
    __builtin_amdgcn_s_setprio(1);
#pragma unroll
    for (int mi = 0; mi < 4; ++mi)
#pragma unroll
      for (int ni = 0; ni < 4; ++ni)
        acc[mi+4][ni] = mfma16(afr[mi], bfr[ni], acc[mi+4][ni]);
    __builtin_amdgcn_s_setprio(0);
    if (tt + 2 < NT) asm volatile("s_waitcnt vmcnt(4)" ::: "memory");
    else             asm volatile("s_waitcnt vmcnt(0)" ::: "memory");
    __builtin_amdgcn_s_barrier();
  }

  __syncthreads();
  constexpr int EPLD = 68;
  float* epw = (float*)sm + w*(16*EPLD);
  const int growbase = bm*256 + wr*128;
  const int gcolbase = bn*256 + wc*64;
#pragma unroll
  for (int mi = 0; mi < 8; ++mi){
#pragma unroll
    for (int ni = 0; ni < 4; ++ni){
      int col = gcolbase + ni*16 + lr;
      float bv = bias ? bias[col < N ? col : N-1] : 0.f;
#pragma unroll
      for (int rr = 0; rr < 4; ++rr)
        epw[(lg*4 + rr)*EPLD + ni*16 + lr] = acc[mi][ni][rr] + bv;
    }
    asm volatile("s_waitcnt lgkmcnt(0)" ::: "memory");
#pragma unroll
    for (int ps = 0; ps < 4; ++ps){
      int rloc = ps*4 + (l >> 4);
      int row = growbase + mi*16 + rloc;
      int col = gcolbase + (l & 15)*4;
      f32x4 v4 = *(const f32x4*)&epw[rloc*EPLD + (l & 15)*4];
      if (row < M){
        if (col + 3 < N) *(f32x4*)(Cout + (u64)row*N + col) = v4;
        else {
#pragma unroll
          for (int j = 0; j < 4; ++j)
            if (col + j < N) Cout[(u64)row*N + col + j] = v4[j];
        }
      }
    }
    asm volatile("s_waitcnt lgkmcnt(0)" ::: "memory");
  }
}

// ---------------------------------------------------------------- flash attention, no-max softmax, 32 q-rows/wave
__global__ __launch_bounds__(256)
void attn_kernel(const u16* __restrict__ qkv, const u16* __restrict__ vt,
                 u16* __restrict__ ob)
{
  __shared__ u16 p_lds[4][32][72];
  const int t = threadIdx.x, w = t >> 6, ll = t & 63;
  const int lr = ll & 15, lg = ll >> 4;
  const int qt = blockIdx.x, h = blockIdx.y, b = blockIdx.z;
  const int q0 = qt*128 + w*32;
  const float C = 0.125f * 1.44269504f;   // 1/sqrt(64) * log2(e)

  short8 qf[2][2];
#pragma unroll
  for (int f = 0; f < 2; ++f){
    const u16* qrow = qkv + (u64)(b*512 + q0 + f*16 + lr)*2304 + h*64 + 8*lg;
    qf[f][0] = *(const short8*)qrow;
    qf[f][1] = *(const short8*)(qrow + 32);
  }

  const u16* kbh = qkv + (u64)(b*512)*2304 + 768 + h*64;
  const u16* vth = vt + (u64)(b*12 + h)*64*512;

  f32x4 lacc[2] = {};
  f32x4 o_acc[2][4] = {};

  for (int jt = 0; jt < 8; ++jt){
    const int jb = jt*64;
    f32x4 s[2][4] = {};
#pragma unroll
    for (int jn = 0; jn < 4; ++jn){
      const u16* kr = kbh + (u64)(jb + jn*16 + lr)*2304 + 8*lg;
      short8 kf0 = *(const short8*)kr;
      short8 kf1 = *(const short8*)(kr + 32);
#pragma unroll
      for (int f = 0; f < 2; ++f){
        s[f][jn] = mfma16(qf[f][0], kf0, s[f][jn]);
        s[f][jn] = mfma16(qf[f][1], kf1, s[f][jn]);
      }
    }
#pragma unroll
    for (int f = 0; f < 2; ++f)
#pragma unroll
      for (int jn = 0; jn < 4; ++jn)
#pragma unroll
        for (int r = 0; r < 4; ++r){
          float pv = exp2f(s[f][jn][r]*C);
          lacc[f][r] += pv;
          p_lds[w][f*16 + 4*lg + r][jn*16 + lr] = f2bf(pv);
        }
    // per-wave LDS region: wave-local wait suffices (DS pipe in-order per wave)
    asm volatile("s_waitcnt lgkmcnt(0)" ::: "memory");
    short8 pa[2][2];
#pragma unroll
    for (int f = 0; f < 2; ++f){
      pa[f][0] = *(const short8*)(&p_lds[w][f*16 + lr][8*lg]);
      pa[f][1] = *(const short8*)(&p_lds[w][f*16 + lr][32 + 8*lg]);
    }
#pragma unroll
    for (int nd = 0; nd < 4; ++nd){
      const u16* vr = vth + (u64)(nd*16 + lr)*512 + jb + 8*lg;
      short8 vf0 = *(const short8*)vr;
      short8 vf1 = *(const short8*)(vr + 32);
#pragma unroll
      for (int f = 0; f < 2; ++f){
        o_acc[f][nd] = mfma16(pa[f][0], vf0, o_acc[f][nd]);
        o_acc[f][nd] = mfma16(pa[f][1], vf1, o_acc[f][nd]);
      }
    }
    asm volatile("s_waitcnt lgkmcnt(0)" ::: "memory");
  }
  float l_r[2][4];
#pragma unroll
  for (int f = 0; f < 2; ++f)
#pragma unroll
    for (int r = 0; r < 4; ++r){
      float v = lacc[f][r];
#pragma unroll
      for (int m = 1; m < 16; m <<= 1) v += __shfl_xor(v, m);
      l_r[f][r] = 1.f / v;
    }
#pragma unroll
  for (int f = 0; f < 2; ++f)
#pragma unroll
    for (int nd = 0; nd < 4; ++nd)
#pragma unroll
      for (int r = 0; r < 4; ++r)
        p_lds[w][f*16 + 4*lg + r][nd*16 + lr] = f2bf(o_acc[f][nd][r]*l_r[f][r]);
  asm volatile("s_waitcnt lgkmcnt(0)" ::: "memory");
#pragma unroll
  for (int ps = 0; ps < 4; ++ps){
    int row = ps*8 + (ll >> 3);
    short8 ov = *(const short8*)(&p_lds[w][row][(ll & 7)*8]);
    *(short8*)(ob + (u64)(b*512 + q0 + row)*768 + h*64 + (ll & 7)*8) = ov;
  }
}

// ---------------------------------------------------------------- host
extern "C" void kernel_launch(void* const* d_in, const int* in_sizes, int n_in,
                              void* d_out, int out_size, void* d_ws, size_t ws_size,
                              hipStream_t stream)
{
  const int*   token_ids  = (const int*)  d_in[0];
  const int*   segment_ids= (const int*)  d_in[1];
  const int*   mask_ids   = (const int*)  d_in[2];
  const float* tok_emb    = (const float*)d_in[3];
  const float* pos_emb    = (const float*)d_in[4];
  const float* seg_emb    = (const float*)d_in[5];
  const float* dense_w    = (const float*)d_in[6];
  const float* dense_b    = (const float*)d_in[7];
  const float* Wq = (const float*)d_in[8];  const float* bq = (const float*)d_in[9];
  const float* Wk = (const float*)d_in[10]; const float* bk = (const float*)d_in[11];
  const float* Wv = (const float*)d_in[12]; const float* bv = (const float*)d_in[13];
  const float* Wo = (const float*)d_in[14]; const float* bo = (const float*)d_in[15];
  const float* W1 = (const float*)d_in[16]; const float* b1 = (const float*)d_in[17];
  const float* W2 = (const float*)d_in[18]; const float* b2 = (const float*)d_in[19];
  const float* g1 = (const float*)d_in[20]; const float* be1= (const float*)d_in[21];
  const float* g2 = (const float*)d_in[22]; const float* be2= (const float*)d_in[23];

  char* p = (char*)d_ws;
  auto alloc = [&](size_t bytes)->char*{
    char* r = p; p += (bytes + 255) & ~(size_t)255; return r;
  };
  const u64 T = 8192;
  u16*   y    = (u16*)  alloc(T*768*2);   // bf16 pre-LN sum (GEMM + bias + residual)
  u16*   xb   = (u16*)  alloc(T*768*2);   // bf16 post-LN residual stream
  u16*   qkvb = (u16*)  alloc(T*2304*2);  // Q,K parts (V goes straight to vT)
  u16*   vT   = (u16*)  alloc(T*768*2);
  u16*   obuf = (u16*)  alloc(T*768*2);
  u16*   h1b  = (u16*)  alloc(T*3072*2);
  u16*   wqkv = (u16*)  alloc((u64)2304*768*2);
  u16*   wob  = (u16*)  alloc((u64)768*768*2);
  u16*   w1b  = (u16*)  alloc((u64)3072*768*2);
  u16*   w2b  = (u16*)  alloc((u64)3072*768*2);
  float* bqkv = (float*)alloc((u64)12*2304*4);
  u16*   dwb  = h1b;   // reuse (dense_w bf16 = 46.9 MB <= h1b 50.3 MB)

  if ((size_t)(p - (char*)d_ws) > ws_size) return;

  embed_kernel<<<dim3(8192), dim3(256), 0, stream>>>(
      token_ids, segment_ids, tok_emb, pos_emb, seg_emb, xb);
  concat_bias<<<dim3(12), dim3(256), 0, stream>>>(bq, bk, bv, bqkv);
  cvt_layer<<<dim3(6912), dim3(256), 0, stream>>>(
      (const float4*)Wq, (const float4*)Wk, (const float4*)Wv, (const float4*)Wo,
      (const float4*)W1, (const float4*)W2,
      (ushort4*)wqkv, (ushort4*)wob, (ushort4*)w1b, (ushort4*)w2b);

  for (int l = 0; l < 12; ++l){
    // QKV: [8192,768] @ [2304,768]^T -> Q,K to qkvb; V transposed to vT in-epilogue
    gemm3r<1><<<dim3(64*18), dim3(256), 0, stream>>>(xb, wqkv, bqkv + (u64)l*2304, nullptr,
                                                     vT, qkvb, 8192, 2304, 768, 64);

    attn_kernel<<<dim3(4, 12, 16), dim3(256), 0, stream>>>(qkvb, vT, obuf);

    // o-proj + residual: y(bf16) = obuf@Wo^T + bo + bf2f(xb)
    gemm3r<0><<<dim3(64*6), dim3(256), 0, stream>>>(obuf, wob, bo + (u64)l*768, xb,
                                                    nullptr, y, 8192, 768, 768, 64);
    ln_wave<<<dim3(2048), dim3(256), 0, stream>>>(y, g1 + (u64)l*768, be1 + (u64)l*768, xb);

    // FFN1: [8192,768] @ [3072,768]^T -> bf16 + GELU
    gemm3r<2><<<dim3(64*24), dim3(256), 0, stream>>>(xb, w1b, b1 + (u64)l*3072, nullptr,
                                                     nullptr, h1b, 8192, 3072, 768, 64);
    // FFN2 + residual: y(bf16) = h1b@W2^T + b2 + bf2f(xb)
    gemm3r<0><<<dim3(64*6), dim3(256), 0, stream>>>(h1b, w2b, b2 + (u64)l*768, xb,
                                                    nullptr, y, 8192, 768, 3072, 64);
    if (l < 11){
      // fused: ln2(l) + weight conversion for layer l+1
      ln2cvt<<<dim3(2048 + 6912), dim3(256), 0, stream>>>(
          y, g2 + (u64)l*768, be2 + (u64)l*768, xb,
          (const float4*)(Wq + (u64)(l+1)*589824), (const float4*)(Wk + (u64)(l+1)*589824),
          (const float4*)(Wv + (u64)(l+1)*589824), (const float4*)(Wo + (u64)(l+1)*589824),
          (const float4*)(W1 + (u64)(l+1)*2359296), (const float4*)(W2 + (u64)(l+1)*2359296),
          (ushort4*)wqkv, (ushort4*)wob, (ushort4*)w1b, (ushort4*)w2b);
    } else {
      ln_wave<<<dim3(2048), dim3(256), 0, stream>>>(y, g2 + (u64)l*768, be2 + (u64)l*768, xb);
    }
  }

  cvt_bf16<<<dim3(22892), dim3(256), 0, stream>>>((const float4*)dense_w, (ushort4*)dwb, 5860224);
  // vocab: gathers masked rows from xb directly via mask_ids
  gemm8v<<<dim3(5*120), dim3(512), 0, stream>>>(xb, mask_ids, dwb, dense_b, (float*)d_out,
                                                1232, 30522, 768, 5);
}